// Round 6
// baseline (439.823 us; speedup 1.0000x reference)
//
#include <hip/hip_runtime.h>
#include <hip/hip_bf16.h>
#include <math.h>

#define BB 2
#define MM 2048
#define DD 1024
#define HH 16
#define DHH 64
#define FF_ 2624
#define FFP 2688            // FF padded to /128
#define TT (BB*MM)          // 4096

typedef unsigned short u16;
typedef __attribute__((ext_vector_type(4))) unsigned short ushort4v;
typedef __attribute__((ext_vector_type(8))) short short8;
typedef __attribute__((ext_vector_type(4))) float floatx4;
typedef __attribute__((ext_vector_type(16))) float floatx16;

#define SCALE2 0.18033688011112043f   // 0.125 * log2(e)

// counted-vmcnt + compiler fences for the raw-barrier pipeline
#define WAITVM(N) asm volatile("s_waitcnt vmcnt(" #N ")" ::: "memory")
#define CFENCE()  asm volatile("" ::: "memory")

__device__ __forceinline__ u16 f2bf(float f) {
    __hip_bfloat16 h = __float2bfloat16(f);
    return *(u16*)&h;
}
__device__ __forceinline__ float bf2f(u16 u) {
    __hip_bfloat16 h; *(u16*)&h = u;
    return __bfloat162float(h);
}
__device__ __forceinline__ float gelu_exact(float x) {
    return 0.5f * x * (1.0f + erff(x * 0.70710678118654752f));
}
__device__ __forceinline__ void gload_lds16(const void* g, void* l) {
    __builtin_amdgcn_global_load_lds(
        (const __attribute__((address_space(1))) unsigned int*)g,
        (__attribute__((address_space(3))) unsigned int*)l, 16, 0, 0);
}
__device__ __forceinline__ unsigned int cvt_pk_bf16(float a, float b) {
    unsigned int r;
    asm("v_cvt_pk_bf16_f32 %0, %1, %2" : "=v"(r) : "v"(a), "v"(b));
    return r;
}
__device__ __forceinline__ short8 pack8(float a0, float a1, float a2, float a3,
                                        float a4, float a5, float a6, float a7) {
    union { unsigned int u[4]; short8 s; } r;
    r.u[0] = cvt_pk_bf16(a0, a1); r.u[1] = cvt_pk_bf16(a2, a3);
    r.u[2] = cvt_pk_bf16(a4, a5); r.u[3] = cvt_pk_bf16(a6, a7);
    return r.s;
}

// bijective XCD swizzle (grid counts all divisible by 8 here; guarded anyway)
__device__ __forceinline__ int xcd_swizzle(int id, int nb) {
    if (nb & 7) return id;
    return (id & 7) * (nb >> 3) + (id >> 3);
}

// ---------------- fused weight conversion + rope table (one dispatch) -------------
__global__ void cvt_all(const float* __restrict__ wqkv, const float* __restrict__ wo,
                        const float* __restrict__ wi, const float* __restrict__ womlp,
                        u16* __restrict__ dqkv, u16* __restrict__ dwo,
                        u16* __restrict__ dinp, u16* __restrict__ dgate,
                        u16* __restrict__ dmlp, float2* __restrict__ tab) {
    int bid = blockIdx.x, tid = threadIdx.x;
    if (bid < 3072) {
        int i = (bid * 256 + tid) * 4;
        float4 v = *(const float4*)(wqkv + i);
        ushort4v o = {f2bf(v.x), f2bf(v.y), f2bf(v.z), f2bf(v.w)};
        *(ushort4v*)(dqkv + i) = o;
    } else if (bid < 4096) {
        int i = ((bid - 3072) * 256 + tid) * 4;
        float4 v = *(const float4*)(wo + i);
        ushort4v o = {f2bf(v.x), f2bf(v.y), f2bf(v.z), f2bf(v.w)};
        *(ushort4v*)(dwo + i) = o;
    } else if (bid < 4096 + 2 * FFP) {
        int seg = (bid - 4096) / FFP;          // 0: inp, 1: gate
        int row = (bid - 4096) % FFP;
        u16* dst = seg ? dgate : dinp;
        const float* src = wi + (size_t)(seg ? FF_ : 0) * DD;
        int c = tid * 4;
        ushort4v o = {0, 0, 0, 0};
        if (row < FF_) {
            float4 v = *(const float4*)(src + (size_t)row * DD + c);
            o.x = f2bf(v.x); o.y = f2bf(v.y); o.z = f2bf(v.z); o.w = f2bf(v.w);
        }
        *(ushort4v*)(dst + (size_t)row * DD + c) = o;
    } else if (bid < 4096 + 2 * FFP + 1024) {
        int row = bid - 4096 - 2 * FFP;        // 0..1023
        for (int c = tid * 4; c < FFP; c += 1024) {
            ushort4v o = {0, 0, 0, 0};
            if (c < FF_) {
                float4 v = *(const float4*)(womlp + (size_t)row * FF_ + c);
                o.x = f2bf(v.x); o.y = f2bf(v.y); o.z = f2bf(v.z); o.w = f2bf(v.w);
            }
            *(ushort4v*)(dmlp + (size_t)row * FFP + c) = o;
        }
    } else {
        // rope table: tab[mi*32 + i] = (cos, sin) of mi * 10000^(-i/32)
        int bq = bid - (4096 + 2 * FFP + 1024);   // 0..63
        int base = bq * 1024;
        for (int idx = tid; idx < 1024; idx += 256) {
            int e = base + idx;
            int mi = e >> 5, i = e & 31;
            float fr = (float)mi * powf(10000.0f, -(float)i / 32.0f);
            tab[e] = make_float2(cosf(fr), sinf(fr));
        }
    }
}

// ---------------- LayerNorm: fp32 in -> bf16 out ----------------------------------
__global__ void ln_kernel(const float* __restrict__ x, const float* __restrict__ w,
                          const float* __restrict__ b, u16* __restrict__ out) {
    int row = blockIdx.x;
    int tid = threadIdx.x;
    const float4 v = ((const float4*)(x + (size_t)row * DD))[tid];
    float s  = v.x + v.y + v.z + v.w;
    float ss = v.x*v.x + v.y*v.y + v.z*v.z + v.w*v.w;
    #pragma unroll
    for (int o = 32; o > 0; o >>= 1) { s += __shfl_down(s, o); ss += __shfl_down(ss, o); }
    __shared__ float sbuf[4], ssbuf[4];
    int wid = tid >> 6;
    if ((tid & 63) == 0) { sbuf[wid] = s; ssbuf[wid] = ss; }
    __syncthreads();
    float st  = sbuf[0] + sbuf[1] + sbuf[2] + sbuf[3];
    float sst = ssbuf[0] + ssbuf[1] + ssbuf[2] + ssbuf[3];
    float mean = st * (1.0f / DD);
    float var  = sst * (1.0f / DD) - mean * mean;
    float rstd = rsqrtf(var + 1e-5f);
    const float4 wv = ((const float4*)w)[tid];
    const float4 bv = ((const float4*)b)[tid];
    ushort4v o;
    o.x = f2bf((v.x - mean) * rstd * wv.x + bv.x);
    o.y = f2bf((v.y - mean) * rstd * wv.y + bv.y);
    o.z = f2bf((v.z - mean) * rstd * wv.z + bv.z);
    o.w = f2bf((v.w - mean) * rstd * wv.w + bv.w);
    ((ushort4v*)(out + (size_t)row * DD))[tid] = o;
}

// =============== depth-2 counted-vmcnt GEMM core (BK=32, 3 LDS buffers) ===========

// ---------------- std GEMM, BM=128 x BN=64: C = A[TxK] * W[NxK]^T -----------------
// MODE 0: +bias(optional fp32)   MODE 1: +add(fp32), fp32 out
template<int MODE, bool OUT_BF16>
__global__ __launch_bounds__(256, 4)
void mfma_gemm64(const u16* __restrict__ A, const u16* __restrict__ W,
                 const float* __restrict__ bias, const void* __restrict__ add,
                 void* __restrict__ Cout, int N, int K) {
    __shared__ u16 As[3][128 * 32];
    __shared__ u16 Bs[3][64 * 32];
    int tid = threadIdx.x;
    int w = tid >> 6, lane = tid & 63;
    int q = lane >> 4, m = lane & 15;

    int nbx = gridDim.x;
    int id = xcd_swizzle(blockIdx.y * nbx + blockIdx.x, nbx * gridDim.y);
    int bx = id % nbx, by = id / nbx;
    int row0 = by * 128, col0 = bx * 64;
    int wm = (w >> 1) * 64, wn = (w & 1) * 32;

    floatx4 acc[4][2];
    #pragma unroll
    for (int i = 0; i < 4; i++)
        #pragma unroll
        for (int j = 0; j < 2; j++)
            acc[i][j] = (floatx4){0.f, 0.f, 0.f, 0.f};

    int lrow = lane >> 2;
    int lcg  = (lane & 3) ^ ((lrow >> 1) & 3);
    const u16* Ag = A + (size_t)(row0 + w * 32 + lrow) * K + lcg * 8;
    const u16* Bg = W + (size_t)(col0 + w * 16 + lrow) * K + lcg * 8;
    int NT = K >> 5;
    int slot8 = (q ^ ((m >> 1) & 3)) * 8;

    auto stage = [&](int t, int buf) {
        const u16* Aq = Ag + (size_t)t * 32;
        const u16* Bq = Bg + (size_t)t * 32;
        gload_lds16(Aq,                  &As[buf][(w * 32) * 32]);
        gload_lds16(Aq + (size_t)16 * K, &As[buf][(w * 32 + 16) * 32]);
        gload_lds16(Bq,                  &Bs[buf][(w * 16) * 32]);
    };
    stage(0, 0); stage(1, 1);   // 6 loads/wave outstanding

    int cur = 0;
    for (int t = 0; t < NT; ++t) {
        if (t + 2 < NT) {
            int nxt = cur + 2; if (nxt >= 3) nxt -= 3;
            stage(t + 2, nxt);
            WAITVM(6);          // tile t landed; t+1,t+2 in flight
        } else if (t + 2 == NT) {
            WAITVM(3);
        } else {
            WAITVM(0);
        }
        __builtin_amdgcn_s_barrier();
        CFENCE();
        short8 af[4], bf[2];
        #pragma unroll
        for (int f = 0; f < 4; f++)
            af[f] = *(const short8*)&As[cur][(wm + f * 16 + m) * 32 + slot8];
        #pragma unroll
        for (int f = 0; f < 2; f++)
            bf[f] = *(const short8*)&Bs[cur][(wn + f * 16 + m) * 32 + slot8];
        __builtin_amdgcn_s_setprio(1);
        #pragma unroll
        for (int mf = 0; mf < 4; mf++)
            #pragma unroll
            for (int nf = 0; nf < 2; nf++)
                acc[mf][nf] = __builtin_amdgcn_mfma_f32_16x16x32_bf16(
                    af[mf], bf[nf], acc[mf][nf], 0, 0, 0);
        __builtin_amdgcn_s_setprio(0);
        if (t + 1 < NT) {
            __builtin_amdgcn_s_barrier();   // reads of buf[cur] done before restage
            CFENCE();
        }
        cur = (cur + 1 == 3) ? 0 : cur + 1;
    }

    #pragma unroll
    for (int nf = 0; nf < 2; nf++) {
        int col = col0 + wn + nf * 16 + m;
        float bv = 0.f;
        if (MODE == 0 && bias) bv = bias[col];
        #pragma unroll
        for (int mf = 0; mf < 4; mf++) {
            #pragma unroll
            for (int r = 0; r < 4; r++) {
                int row = row0 + wm + mf * 16 + q * 4 + r;
                size_t idx = (size_t)row * N + col;
                float vacc = acc[mf][nf][r] + bv;
                if (MODE == 1) vacc += ((const float*)add)[idx];
                if (OUT_BF16) ((u16*)Cout)[idx] = f2bf(vacc);
                else          ((float*)Cout)[idx] = vacc;
            }
        }
    }
}

// ---------------- fused QKV GEMM (BM=128 x BN=64) + bias + RoPE + scatter ---------
__global__ __launch_bounds__(256, 4)
void mfma_gemm_qkv(const u16* __restrict__ A, const u16* __restrict__ W,
                   const float* __restrict__ bias, const float2* __restrict__ tab,
                   u16* __restrict__ qb, u16* __restrict__ kb, u16* __restrict__ vtb) {
    __shared__ u16 As[3][128 * 32];
    __shared__ u16 Bs[3][64 * 32];
    int tid = threadIdx.x;
    int w = tid >> 6, lane = tid & 63;
    int q = lane >> 4, m = lane & 15;

    int nbx = gridDim.x;
    int id = xcd_swizzle(blockIdx.y * nbx + blockIdx.x, nbx * gridDim.y);
    int bx = id % nbx, by = id / nbx;
    int row0 = by * 128, col0 = bx * 64;
    int wm = w * 32;

    floatx4 acc[2][4];
    #pragma unroll
    for (int i = 0; i < 2; i++)
        #pragma unroll
        for (int j = 0; j < 4; j++)
            acc[i][j] = (floatx4){0.f, 0.f, 0.f, 0.f};

    int lrow = lane >> 2;
    int lcg  = (lane & 3) ^ ((lrow >> 1) & 3);
    const u16* Ag = A + (size_t)(row0 + w * 32 + lrow) * DD + lcg * 8;
    const u16* Bg = W + (size_t)(col0 + w * 16 + lrow) * DD + lcg * 8;
    const int NT = DD >> 5;   // 32
    int slot8 = (q ^ ((m >> 1) & 3)) * 8;

    auto stage = [&](int t, int buf) {
        const u16* Aq = Ag + (size_t)t * 32;
        const u16* Bq = Bg + (size_t)t * 32;
        gload_lds16(Aq,                   &As[buf][(w * 32) * 32]);
        gload_lds16(Aq + (size_t)16 * DD, &As[buf][(w * 32 + 16) * 32]);
        gload_lds16(Bq,                   &Bs[buf][(w * 16) * 32]);
    };
    stage(0, 0); stage(1, 1);

    int cur = 0;
    for (int t = 0; t < NT; ++t) {
        if (t + 2 < NT) {
            int nxt = cur + 2; if (nxt >= 3) nxt -= 3;
            stage(t + 2, nxt);
            WAITVM(6);
        } else if (t + 2 == NT) {
            WAITVM(3);
        } else {
            WAITVM(0);
        }
        __builtin_amdgcn_s_barrier();
        CFENCE();
        short8 af[2], bf[4];
        #pragma unroll
        for (int f = 0; f < 2; f++)
            af[f] = *(const short8*)&As[cur][(wm + f * 16 + m) * 32 + slot8];
        #pragma unroll
        for (int f = 0; f < 4; f++)
            bf[f] = *(const short8*)&Bs[cur][(f * 16 + m) * 32 + slot8];
        __builtin_amdgcn_s_setprio(1);
        #pragma unroll
        for (int mf = 0; mf < 2; mf++)
            #pragma unroll
            for (int nf = 0; nf < 4; nf++)
                acc[mf][nf] = __builtin_amdgcn_mfma_f32_16x16x32_bf16(
                    af[mf], bf[nf], acc[mf][nf], 0, 0, 0);
        __builtin_amdgcn_s_setprio(0);
        if (t + 1 < NT) {
            __builtin_amdgcn_s_barrier();
            CFENCE();
        }
        cur = (cur + 1 == 3) ? 0 : cur + 1;
    }

    // ---- fused epilogue ----
    int seg = col0 >> 6;             // 0..15 q, 16..31 k, 32..47 v
    int b   = row0 >> 11;            // batch (uniform per block)
    int mi0 = (row0 & 2047) + wm;

    float b0[4];
    #pragma unroll
    for (int nf = 0; nf < 4; nf++) b0[nf] = bias[col0 + nf * 16 + m];

    if (seg < 32) {
        int hq = seg & 15;
        u16* dst = (seg < 16 ? qb : kb) + (size_t)(b * HH + hq) * MM * DHH;
        #pragma unroll
        for (int mf = 0; mf < 2; mf++) {
            #pragma unroll
            for (int r = 0; r < 4; r++) {
                int mi = mi0 + mf * 16 + q * 4 + r;
                float2 cs0 = tab[mi * 32 + m];        // pair (m, m+32)
                float2 cs1 = tab[mi * 32 + 16 + m];   // pair (16+m, 48+m)
                float a0 = acc[mf][0][r] + b0[0];
                float a1 = acc[mf][1][r] + b0[1];
                float a2 = acc[mf][2][r] + b0[2];
                float a3 = acc[mf][3][r] + b0[3];
                size_t base = (size_t)mi * DHH;
                dst[base + m]      = f2bf(a0 * cs0.x - a2 * cs0.y);
                dst[base + 32 + m] = f2bf(a0 * cs0.y + a2 * cs0.x);
                dst[base + 16 + m] = f2bf(a1 * cs1.x - a3 * cs1.y);
                dst[base + 48 + m] = f2bf(a1 * cs1.y + a3 * cs1.x);
            }
        }
    } else {
        int hv = seg & 15;
        u16* dst = vtb + (size_t)(b * HH + hv) * DHH * MM;
        #pragma unroll
        for (int nf = 0; nf < 4; nf++) {
            int d = nf * 16 + m;
            #pragma unroll
            for (int mf = 0; mf < 2; mf++) {
                int mi = mi0 + mf * 16 + q * 4;
                ushort4v o;
                o.x = f2bf(acc[mf][nf][0] + b0[nf]);
                o.y = f2bf(acc[mf][nf][1] + b0[nf]);
                o.z = f2bf(acc[mf][nf][2] + b0[nf]);
                o.w = f2bf(acc[mf][nf][3] + b0[nf]);
                *(ushort4v*)(dst + (size_t)d * MM + mi) = o;
            }
        }
    }
}

// ---------------- dual-B MLP GEMM: all-register, zero-LDS, zero-barrier -----------
// BM=128 x BN=128, 4 waves 2x2, wave tile 64x64 (4x4 frags of 16x16x32).
// Operand fragments loaded DIRECTLY global->VGPR: lane(q,m) frag f reads 16B at
// row (f*16+m), k-chunk q*8 -- a wave-load = exactly 16 full 64B lines (L2-resident
// weights). 2-deep register double-buffer, statically unrolled (no runtime set
// index). No __syncthreads anywhere: waves fully independent, compiler emits
// exact vmcnt for reg deps. 12 loads -> 32 MFMA per BK=32 iter (43.7 FLOP/L2-byte).
__global__ __launch_bounds__(256, 2)
void mfma_gemm_glu(const u16* __restrict__ A, const u16* __restrict__ W1,
                   const u16* __restrict__ W2, u16* __restrict__ Cout) {
    int tid = threadIdx.x;
    int w = tid >> 6, lane = tid & 63;
    int q = lane >> 4, m = lane & 15;

    int nbx = gridDim.x;   // FFP/128 = 21
    int id = xcd_swizzle(blockIdx.y * nbx + blockIdx.x, nbx * gridDim.y);
    int bx = id % nbx, by = id / nbx;
    int row0 = by * 128, col0 = bx * 128;
    int wm = (w >> 1) * 64, wn = (w & 1) * 64;

    floatx4 acc1[4][4], acc2[4][4];
    #pragma unroll
    for (int i = 0; i < 4; i++)
        #pragma unroll
        for (int j = 0; j < 4; j++) {
            acc1[i][j] = (floatx4){0.f, 0.f, 0.f, 0.f};
            acc2[i][j] = (floatx4){0.f, 0.f, 0.f, 0.f};
        }

    const u16* Ab  = A  + (size_t)(row0 + wm + m) * DD + q * 8;
    const u16* B1b = W1 + (size_t)(col0 + wn + m) * DD + q * 8;
    const u16* B2b = W2 + (size_t)(col0 + wn + m) * DD + q * 8;

    short8 a[2][4], b1[2][4], b2[2][4];   // literal-indexed only (static regs)

#define GLU_LOAD(S, T) do {                                                   \
    _Pragma("unroll")                                                         \
    for (int f = 0; f < 4; f++) {                                             \
        a[S][f]  = *(const short8*)(Ab  + (size_t)f * 16 * DD + (T) * 32);    \
        b1[S][f] = *(const short8*)(B1b + (size_t)f * 16 * DD + (T) * 32);    \
        b2[S][f] = *(const short8*)(B2b + (size_t)f * 16 * DD + (T) * 32);    \
    } } while (0)

#define GLU_MFMA(S) do {                                                      \
    __builtin_amdgcn_s_setprio(1);                                            \
    _Pragma("unroll")                                                         \
    for (int mf = 0; mf < 4; mf++)                                            \
        _Pragma("unroll")                                                     \
        for (int nf = 0; nf < 4; nf++) {                                      \
            acc1[mf][nf] = __builtin_amdgcn_mfma_f32_16x16x32_bf16(           \
                a[S][mf], b1[S][nf], acc1[mf][nf], 0, 0, 0);                  \
            acc2[mf][nf] = __builtin_amdgcn_mfma_f32_16x16x32_bf16(           \
                a[S][mf], b2[S][nf], acc2[mf][nf], 0, 0, 0);                  \
        }                                                                     \
    __builtin_amdgcn_s_setprio(0); } while (0)

    const int NT = DD >> 5;   // 32 (even)
    GLU_LOAD(0, 0);
    for (int t = 0; t + 2 < NT; t += 2) {
        GLU_LOAD(1, t + 1);
        GLU_MFMA(0);
        GLU_LOAD(0, t + 2);
        GLU_MFMA(1);
    }
    GLU_LOAD(1, NT - 1);
    GLU_MFMA(0);
    GLU_MFMA(1);
#undef GLU_LOAD
#undef GLU_MFMA

    #pragma unroll
    for (int nf = 0; nf < 4; nf++) {
        int col = col0 + wn + nf * 16 + m;
        #pragma unroll
        for (int mf = 0; mf < 4; mf++) {
            #pragma unroll
            for (int r = 0; r < 4; r++) {
                int row = row0 + wm + mf * 16 + q * 4 + r;
                Cout[(size_t)row * FFP + col] =
                    f2bf(gelu_exact(acc1[mf][nf][r]) * acc2[mf][nf][r]);
            }
        }
    }
}

// ---------------- MFMA flash attention, 32x32 swapped-QK^T, in-register softmax ----
// 4 waves x 32 Q-rows (128/block, grid 512). St = mfma(K,Q) -> lane owns Q-row
// (col=lane&31): softmax denominator is one per-lane scalar, P stays in registers.
// K rows sigma-staged (swap bits 2<->3 of LDS row) so St's C-layout regs land in
// PV A-fragment order: pa[s] = p[8s..8s+7] -> 16 cvt_pk, zero cross-lane ops.
__global__ __launch_bounds__(256, 2)
void flash_attn_mfma32(const u16* __restrict__ qp, const u16* __restrict__ kp,
                       const u16* __restrict__ vt, const int* __restrict__ mask,
                       u16* __restrict__ out) {
    __shared__ __align__(16) u16 Ks[2 * 64 * 64];   // [buf][kv(sigma)][chunk swz row&7]
    __shared__ __align__(16) u16 Vs[2 * 64 * 64];   // [buf][d][kv chunk swz row&7]

    int tid = threadIdx.x;
    int w = tid >> 6, lane = tid & 63;
    int col = lane & 31, hi = lane >> 5;
    int mt = blockIdx.x, h = blockIdx.y, b = blockIdx.z;
    int m0 = mt * 128;
    size_t bh = (size_t)(b * HH + h);
    const u16* qg  = qp + (bh * MM + m0 + w * 32) * DHH;
    const u16* kg  = kp + bh * MM * DHH;
    const u16* vtg = vt + bh * DHH * MM;

    // number of valid 64-aligned KV tiles (monotone mask; uniform scalar loads)
    int ntv = 0;
    for (int n = 0; n < MM; n += 64) ntv += (mask[b * MM + n] != 0);

    // Q fragments straight to registers: B-operand Q[qrow=col][k=(2t+hi)*8..+7]
    short8 qf[4];
    #pragma unroll
    for (int t = 0; t < 4; t++)
        qf[t] = *(const short8*)(qg + (size_t)col * DHH + (2 * t + hi) * 8);

    // staging geometry: each gload = 8 LDS rows x 8 chunks; chunk pre-swizzle c^(row&7)
    int lr = lane >> 3, lc = lane & 7;
    int lcg = lc ^ lr;
    int i0 = w * 16 + lr, i1 = i0 + 8;          // this wave's LDS rows
    int sg0 = (i0 & ~12) | ((i0 & 4) << 1) | ((i0 & 8) >> 1);   // sigma(i0)
    int sg1 = (i1 & ~12) | ((i1 & 4) << 1) | ((i1 & 8) >> 1);   // sigma(i1)
    const u16* Kg0 = kg + (size_t)sg0 * DHH + lcg * 8;
    const u16* Kg1 = kg + (size_t)sg1 * DHH + lcg * 8;
    const u16* Vg0 = vtg + (size_t)i0 * MM + lcg * 8;
    const u16* Vg1 = vtg + (size_t)i1 * MM + lcg * 8;
    u16* KL0 = Ks + (w * 16) * 64;
    u16* KL1 = KL0 + 8 * 64;
    u16* VL0 = Vs + (w * 16) * 64;
    u16* VL1 = VL0 + 8 * 64;
    const int BUFO = 64 * 64;   // u16 elements per buffer

    // prologue: stage tile 0 into buf 0 (4 gloads/wave)
    gload_lds16(Kg0, KL0); gload_lds16(Kg1, KL1);
    gload_lds16(Vg0, VL0); gload_lds16(Vg1, VL1);

    floatx16 O0, O1;
    #pragma unroll
    for (int r = 0; r < 16; r++) { O0[r] = 0.f; O1[r] = 0.f; }
    float ls = 0.f;

    int swz = (col & 7) * 8;    // chunk-swizzle term for frag reads

    for (int it = 0; it < ntv; ++it) {
        int cur = it & 1;
        int co = cur * BUFO, po = (cur ^ 1) * BUFO;
        if (it + 1 < ntv) {
            size_t nk = (size_t)(it + 1) * 64;
            gload_lds16(Kg0 + nk * DHH, KL0 + po);
            gload_lds16(Kg1 + nk * DHH, KL1 + po);
            gload_lds16(Vg0 + nk,       VL0 + po);
            gload_lds16(Vg1 + nk,       VL1 + po);
            WAITVM(4);          // current tile landed; next tile in flight
        } else {
            WAITVM(0);
        }
        __builtin_amdgcn_s_barrier();
        CFENCE();

        // ---- St = K(sigma) . Q^T : lane owns Q-row `col`, 16 kv per lane ----
        floatx16 P0, P1;
        #pragma unroll
        for (int r = 0; r < 16; r++) { P0[r] = 0.f; P1[r] = 0.f; }
        #pragma unroll
        for (int t = 0; t < 4; t++) {
            int ck = (((2 * t + hi) * 8) ^ swz);
            short8 kf0 = *(const short8*)&Ks[co + col * 64 + ck];
            short8 kf1 = *(const short8*)&Ks[co + (32 + col) * 64 + ck];
            __builtin_amdgcn_s_setprio(1);
            P0 = __builtin_amdgcn_mfma_f32_32x32x16_bf16(kf0, qf[t], P0, 0, 0, 0);
            P1 = __builtin_amdgcn_mfma_f32_32x32x16_bf16(kf1, qf[t], P1, 0, 0, 0);
            __builtin_amdgcn_s_setprio(0);
        }

        // ---- max-free softmax, in-register; per-lane scalar denominator ----
        #pragma unroll
        for (int r = 0; r < 16; r++) {
            float e0 = exp2f(P0[r] * SCALE2);
            float e1 = exp2f(P1[r] * SCALE2);
            P0[r] = e0; P1[r] = e1;
            ls += e0 + e1;
        }

        // ---- pack P to bf16 A-fragments (sigma makes reg order = frag order) ----
        short8 pa0 = pack8(P0[0], P0[1], P0[2],  P0[3],  P0[4],  P0[5],  P0[6],  P0[7]);
        short8 pa1 = pack8(P0[8], P0[9], P0[10], P0[11], P0[12], P0[13], P0[14], P0[15]);
        short8 pa2 = pack8(P1[0], P1[1], P1[2],  P1[3],  P1[4],  P1[5],  P1[6],  P1[7]);
        short8 pa3 = pack8(P1[8], P1[9], P1[10], P1[11], P1[12], P1[13], P1[14], P1[15]);

        // ---- O += P V  (B-operand Vt[d][kv]) ----
        #pragma unroll
        for (int s = 0; s < 4; s++) {
            int ck = (((2 * s + hi) * 8) ^ swz);
            short8 vf0 = *(const short8*)&Vs[co + col * 64 + ck];
            short8 vf1 = *(const short8*)&Vs[co + (32 + col) * 64 + ck];
            short8 pas = (s == 0) ? pa0 : (s == 1) ? pa1 : (s == 2) ? pa2 : pa3;
            __builtin_amdgcn_s_setprio(1);
            O0 = __builtin_amdgcn_mfma_f32_32x32x16_bf16(pas, vf0, O0, 0, 0, 0);
            O1 = __builtin_amdgcn_mfma_f32_32x32x16_bf16(pas, vf1, O1, 0, 0, 0);
            __builtin_amdgcn_s_setprio(0);
        }
        __builtin_amdgcn_s_barrier();   // buf[cur] reads done before restage
        CFENCE();
    }
    WAITVM(0);      // drain stray prefetch before LDS goes out of scope
    CFENCE();

    // ---- epilogue: denominator = sum over both hi-halves of the Q-row ----
    ls += __shfl_xor(ls, 32);
    float inv = 1.0f / ls;              // valid for qrow = col (both hi lanes)
    float invr[16];
    #pragma unroll
    for (int r = 0; r < 16; r++) {
        int crow = (r & 3) + 8 * (r >> 2) + 4 * hi;   // O-row for this reg
        invr[r] = __shfl(inv, crow, 64);
    }
    u16* ob = out + ((size_t)(b * MM) + m0 + w * 32) * DD + h * DHH;
    #pragma unroll
    for (int r = 0; r < 16; r++) {
        int crow = (r & 3) + 8 * (r >> 2) + 4 * hi;
        ob[(size_t)crow * DD + col]      = f2bf(O0[r] * invr[r]);
        ob[(size_t)crow * DD + 32 + col] = f2bf(O1[r] * invr[r]);
    }
}

extern "C" void kernel_launch(void* const* d_in, const int* in_sizes, int n_in,
                              void* d_out, int out_size, void* d_ws, size_t ws_size,
                              hipStream_t stream) {
    const float* hidden   = (const float*)d_in[0];
    const int*   mask     = (const int*)d_in[1];
    const float* ln1_w    = (const float*)d_in[2];
    const float* ln1_b    = (const float*)d_in[3];
    const float* wqkv_w   = (const float*)d_in[4];
    const float* wqkv_b   = (const float*)d_in[5];
    const float* wo_w     = (const float*)d_in[6];
    const float* ln2_w    = (const float*)d_in[7];
    const float* ln2_b    = (const float*)d_in[8];
    const float* wi_w     = (const float*)d_in[9];
    const float* wo_mlp_w = (const float*)d_in[10];
    float* out = (float*)d_out;

    char* ws = (char*)d_ws;
    u16* wqkv_bf  = (u16*)(ws);                         //  6.00 MB
    u16* wo_bf    = (u16*)(ws + 6291456);               //  2.00 MB
    u16* wi_inp   = (u16*)(ws + 8388608);               //  5.25 MB
    u16* wi_gate  = (u16*)(ws + 13893632);              //  5.25 MB
    u16* womlp_bf = (u16*)(ws + 19398656);              //  5.25 MB
    u16* xn       = (u16*)(ws + 24903680);              //  8 MB [4096][1024]
    float2* rtab  = (float2*)(ws + 33292288);           //  512 KB rope table
    u16* qb       = (u16*)(ws + 58458112);              //  8 MB (B,H,M,DH)
    u16* kb       = (u16*)(ws + 66846720);              //  8 MB
    u16* vtb      = (u16*)(ws + 75235328);              //  8 MB (B,H,DH,M)
    u16* attn_out = (u16*)(ws + 83623936);              //  8 MB
    u16* hb       = (u16*)(ws + 92012544);              //  8 MB
    u16* act      = (u16*)(ws + 58458112);              // 22 MB, reuses qb/kb/vt

    // 0. all weight conversions + rope table (one dispatch)
    cvt_all<<<4096 + 2 * FFP + 1024 + 64, 256, 0, stream>>>(
        wqkv_w, wo_w, wi_w, wo_mlp_w, wqkv_bf, wo_bf, wi_inp, wi_gate, womlp_bf, rtab);
    // 1. LN1
    ln_kernel<<<TT, 256, 0, stream>>>(hidden, ln1_w, ln1_b, xn);
    // 2. fused QKV GEMM + bias + RoPE + V-transpose scatter  (1536 blocks)
    mfma_gemm_qkv<<<dim3(3 * DD / 64, TT / 128), 256, 0, stream>>>(
        xn, wqkv_bf, wqkv_b, rtab, qb, kb, vtb);
    // 3. MFMA flash attention, 32x32 swapped (512 blocks, 128 Q-rows each)
    flash_attn_mfma32<<<dim3(MM / 128, HH, BB), 256, 0, stream>>>(
        qb, kb, vtb, mask, attn_out);
    // 4. x1 = hidden + attn_out @ Wo^T -> d_out (fp32)   (512 blocks)
    mfma_gemm64<1, false><<<dim3(DD / 64, TT / 128), 256, 0, stream>>>(
        attn_out, wo_bf, nullptr, hidden, out, DD, DD);
    // 5. LN2
    ln_kernel<<<TT, 256, 0, stream>>>(out, ln2_w, ln2_b, hb);
    // 6. act = gelu(h@Wi^T) * (h@Wg^T)  all-register GEMM (672 blocks, 21x32)
    mfma_gemm_glu<<<dim3(FFP / 128, TT / 128), 256, 0, stream>>>(
        hb, wi_inp, wi_gate, act);
    // 7. out = out + act @ Wo_mlp^T   (512 blocks)
    mfma_gemm64<1, false><<<dim3(DD / 64, TT / 128), 256, 0, stream>>>(
        act, womlp_bf, nullptr, out, out, DD, FFP);
}

// Round 7
// 379.253 us; speedup vs baseline: 1.1597x; 1.1597x over previous
//
#include <hip/hip_runtime.h>
#include <hip/hip_bf16.h>
#include <math.h>

#define BB 2
#define MM 2048
#define DD 1024
#define HH 16
#define DHH 64
#define FF_ 2624
#define FFP 2688            // FF padded to /128
#define TT (BB*MM)          // 4096

typedef unsigned short u16;
typedef __attribute__((ext_vector_type(4))) unsigned short ushort4v;
typedef __attribute__((ext_vector_type(8))) short short8;
typedef __attribute__((ext_vector_type(4))) float floatx4;
typedef __attribute__((ext_vector_type(16))) float floatx16;

#define SCALE2 0.18033688011112043f   // 0.125 * log2(e)

// counted-vmcnt + compiler fences for the raw-barrier pipeline
#define WAITVM(N) asm volatile("s_waitcnt vmcnt(" #N ")" ::: "memory")
#define CFENCE()  asm volatile("" ::: "memory")

__device__ __forceinline__ u16 f2bf(float f) {
    __hip_bfloat16 h = __float2bfloat16(f);
    return *(u16*)&h;
}
__device__ __forceinline__ float bf2f(u16 u) {
    __hip_bfloat16 h; *(u16*)&h = u;
    return __bfloat162float(h);
}
__device__ __forceinline__ float gelu_exact(float x) {
    return 0.5f * x * (1.0f + erff(x * 0.70710678118654752f));
}
__device__ __forceinline__ void gload_lds16(const void* g, void* l) {
    __builtin_amdgcn_global_load_lds(
        (const __attribute__((address_space(1))) unsigned int*)g,
        (__attribute__((address_space(3))) unsigned int*)l, 16, 0, 0);
}
__device__ __forceinline__ unsigned int cvt_pk_bf16(float a, float b) {
    unsigned int r;
    asm("v_cvt_pk_bf16_f32 %0, %1, %2" : "=v"(r) : "v"(a), "v"(b));
    return r;
}
__device__ __forceinline__ short8 pack8(float a0, float a1, float a2, float a3,
                                        float a4, float a5, float a6, float a7) {
    union { unsigned int u[4]; short8 s; } r;
    r.u[0] = cvt_pk_bf16(a0, a1); r.u[1] = cvt_pk_bf16(a2, a3);
    r.u[2] = cvt_pk_bf16(a4, a5); r.u[3] = cvt_pk_bf16(a6, a7);
    return r.s;
}

// bijective XCD swizzle (grid counts all divisible by 8 here; guarded anyway)
__device__ __forceinline__ int xcd_swizzle(int id, int nb) {
    if (nb & 7) return id;
    return (id & 7) * (nb >> 3) + (id >> 3);
}

// ---------------- fused weight conversion + rope table (one dispatch) -------------
__global__ void cvt_all(const float* __restrict__ wqkv, const float* __restrict__ wo,
                        const float* __restrict__ wi, const float* __restrict__ womlp,
                        u16* __restrict__ dqkv, u16* __restrict__ dwo,
                        u16* __restrict__ dinp, u16* __restrict__ dgate,
                        u16* __restrict__ dmlp, float2* __restrict__ tab) {
    int bid = blockIdx.x, tid = threadIdx.x;
    if (bid < 3072) {
        int i = (bid * 256 + tid) * 4;
        float4 v = *(const float4*)(wqkv + i);
        ushort4v o = {f2bf(v.x), f2bf(v.y), f2bf(v.z), f2bf(v.w)};
        *(ushort4v*)(dqkv + i) = o;
    } else if (bid < 4096) {
        int i = ((bid - 3072) * 256 + tid) * 4;
        float4 v = *(const float4*)(wo + i);
        ushort4v o = {f2bf(v.x), f2bf(v.y), f2bf(v.z), f2bf(v.w)};
        *(ushort4v*)(dwo + i) = o;
    } else if (bid < 4096 + 2 * FFP) {
        int seg = (bid - 4096) / FFP;          // 0: inp, 1: gate
        int row = (bid - 4096) % FFP;
        u16* dst = seg ? dgate : dinp;
        const float* src = wi + (size_t)(seg ? FF_ : 0) * DD;
        int c = tid * 4;
        ushort4v o = {0, 0, 0, 0};
        if (row < FF_) {
            float4 v = *(const float4*)(src + (size_t)row * DD + c);
            o.x = f2bf(v.x); o.y = f2bf(v.y); o.z = f2bf(v.z); o.w = f2bf(v.w);
        }
        *(ushort4v*)(dst + (size_t)row * DD + c) = o;
    } else if (bid < 4096 + 2 * FFP + 1024) {
        int row = bid - 4096 - 2 * FFP;        // 0..1023
        for (int c = tid * 4; c < FFP; c += 1024) {
            ushort4v o = {0, 0, 0, 0};
            if (c < FF_) {
                float4 v = *(const float4*)(womlp + (size_t)row * FF_ + c);
                o.x = f2bf(v.x); o.y = f2bf(v.y); o.z = f2bf(v.z); o.w = f2bf(v.w);
            }
            *(ushort4v*)(dmlp + (size_t)row * FFP + c) = o;
        }
    } else {
        // rope table: tab[mi*32 + i] = (cos, sin) of mi * 10000^(-i/32)
        int bq = bid - (4096 + 2 * FFP + 1024);   // 0..63
        int base = bq * 1024;
        for (int idx = tid; idx < 1024; idx += 256) {
            int e = base + idx;
            int mi = e >> 5, i = e & 31;
            float fr = (float)mi * powf(10000.0f, -(float)i / 32.0f);
            tab[e] = make_float2(cosf(fr), sinf(fr));
        }
    }
}

// ---------------- LayerNorm: fp32 in -> bf16 out ----------------------------------
__global__ void ln_kernel(const float* __restrict__ x, const float* __restrict__ w,
                          const float* __restrict__ b, u16* __restrict__ out) {
    int row = blockIdx.x;
    int tid = threadIdx.x;
    const float4 v = ((const float4*)(x + (size_t)row * DD))[tid];
    float s  = v.x + v.y + v.z + v.w;
    float ss = v.x*v.x + v.y*v.y + v.z*v.z + v.w*v.w;
    #pragma unroll
    for (int o = 32; o > 0; o >>= 1) { s += __shfl_down(s, o); ss += __shfl_down(ss, o); }
    __shared__ float sbuf[4], ssbuf[4];
    int wid = tid >> 6;
    if ((tid & 63) == 0) { sbuf[wid] = s; ssbuf[wid] = ss; }
    __syncthreads();
    float st  = sbuf[0] + sbuf[1] + sbuf[2] + sbuf[3];
    float sst = ssbuf[0] + ssbuf[1] + ssbuf[2] + ssbuf[3];
    float mean = st * (1.0f / DD);
    float var  = sst * (1.0f / DD) - mean * mean;
    float rstd = rsqrtf(var + 1e-5f);
    const float4 wv = ((const float4*)w)[tid];
    const float4 bv = ((const float4*)b)[tid];
    ushort4v o;
    o.x = f2bf((v.x - mean) * rstd * wv.x + bv.x);
    o.y = f2bf((v.y - mean) * rstd * wv.y + bv.y);
    o.z = f2bf((v.z - mean) * rstd * wv.z + bv.z);
    o.w = f2bf((v.w - mean) * rstd * wv.w + bv.w);
    ((ushort4v*)(out + (size_t)row * DD))[tid] = o;
}

// =============== depth-2 counted-vmcnt GEMM core (BK=32, 3 LDS buffers) ===========

// ---------------- std GEMM, BM=128 x BN=64: C = A[TxK] * W[NxK]^T -----------------
// MODE 0: +bias(optional fp32)   MODE 1: +add(fp32), fp32 out
template<int MODE, bool OUT_BF16>
__global__ __launch_bounds__(256, 4)
void mfma_gemm64(const u16* __restrict__ A, const u16* __restrict__ W,
                 const float* __restrict__ bias, const void* __restrict__ add,
                 void* __restrict__ Cout, int N, int K) {
    __shared__ u16 As[3][128 * 32];
    __shared__ u16 Bs[3][64 * 32];
    int tid = threadIdx.x;
    int w = tid >> 6, lane = tid & 63;
    int q = lane >> 4, m = lane & 15;

    int nbx = gridDim.x;
    int id = xcd_swizzle(blockIdx.y * nbx + blockIdx.x, nbx * gridDim.y);
    int bx = id % nbx, by = id / nbx;
    int row0 = by * 128, col0 = bx * 64;
    int wm = (w >> 1) * 64, wn = (w & 1) * 32;

    floatx4 acc[4][2];
    #pragma unroll
    for (int i = 0; i < 4; i++)
        #pragma unroll
        for (int j = 0; j < 2; j++)
            acc[i][j] = (floatx4){0.f, 0.f, 0.f, 0.f};

    int lrow = lane >> 2;
    int lcg  = (lane & 3) ^ ((lrow >> 1) & 3);
    const u16* Ag = A + (size_t)(row0 + w * 32 + lrow) * K + lcg * 8;
    const u16* Bg = W + (size_t)(col0 + w * 16 + lrow) * K + lcg * 8;
    int NT = K >> 5;
    int slot8 = (q ^ ((m >> 1) & 3)) * 8;

    auto stage = [&](int t, int buf) {
        const u16* Aq = Ag + (size_t)t * 32;
        const u16* Bq = Bg + (size_t)t * 32;
        gload_lds16(Aq,                  &As[buf][(w * 32) * 32]);
        gload_lds16(Aq + (size_t)16 * K, &As[buf][(w * 32 + 16) * 32]);
        gload_lds16(Bq,                  &Bs[buf][(w * 16) * 32]);
    };
    stage(0, 0); stage(1, 1);   // 6 loads/wave outstanding

    int cur = 0;
    for (int t = 0; t < NT; ++t) {
        if (t + 2 < NT) {
            int nxt = cur + 2; if (nxt >= 3) nxt -= 3;
            stage(t + 2, nxt);
            WAITVM(6);          // tile t landed; t+1,t+2 in flight
        } else if (t + 2 == NT) {
            WAITVM(3);
        } else {
            WAITVM(0);
        }
        __builtin_amdgcn_s_barrier();
        CFENCE();
        short8 af[4], bf[2];
        #pragma unroll
        for (int f = 0; f < 4; f++)
            af[f] = *(const short8*)&As[cur][(wm + f * 16 + m) * 32 + slot8];
        #pragma unroll
        for (int f = 0; f < 2; f++)
            bf[f] = *(const short8*)&Bs[cur][(wn + f * 16 + m) * 32 + slot8];
        __builtin_amdgcn_s_setprio(1);
        #pragma unroll
        for (int mf = 0; mf < 4; mf++)
            #pragma unroll
            for (int nf = 0; nf < 2; nf++)
                acc[mf][nf] = __builtin_amdgcn_mfma_f32_16x16x32_bf16(
                    af[mf], bf[nf], acc[mf][nf], 0, 0, 0);
        __builtin_amdgcn_s_setprio(0);
        if (t + 1 < NT) {
            __builtin_amdgcn_s_barrier();   // reads of buf[cur] done before restage
            CFENCE();
        }
        cur = (cur + 1 == 3) ? 0 : cur + 1;
    }

    #pragma unroll
    for (int nf = 0; nf < 2; nf++) {
        int col = col0 + wn + nf * 16 + m;
        float bv = 0.f;
        if (MODE == 0 && bias) bv = bias[col];
        #pragma unroll
        for (int mf = 0; mf < 4; mf++) {
            #pragma unroll
            for (int r = 0; r < 4; r++) {
                int row = row0 + wm + mf * 16 + q * 4 + r;
                size_t idx = (size_t)row * N + col;
                float vacc = acc[mf][nf][r] + bv;
                if (MODE == 1) vacc += ((const float*)add)[idx];
                if (OUT_BF16) ((u16*)Cout)[idx] = f2bf(vacc);
                else          ((float*)Cout)[idx] = vacc;
            }
        }
    }
}

// ---------------- fused QKV GEMM (BM=128 x BN=64) + bias + RoPE + scatter ---------
__global__ __launch_bounds__(256, 4)
void mfma_gemm_qkv(const u16* __restrict__ A, const u16* __restrict__ W,
                   const float* __restrict__ bias, const float2* __restrict__ tab,
                   u16* __restrict__ qb, u16* __restrict__ kb, u16* __restrict__ vtb) {
    __shared__ u16 As[3][128 * 32];
    __shared__ u16 Bs[3][64 * 32];
    int tid = threadIdx.x;
    int w = tid >> 6, lane = tid & 63;
    int q = lane >> 4, m = lane & 15;

    int nbx = gridDim.x;
    int id = xcd_swizzle(blockIdx.y * nbx + blockIdx.x, nbx * gridDim.y);
    int bx = id % nbx, by = id / nbx;
    int row0 = by * 128, col0 = bx * 64;
    int wm = w * 32;

    floatx4 acc[2][4];
    #pragma unroll
    for (int i = 0; i < 2; i++)
        #pragma unroll
        for (int j = 0; j < 4; j++)
            acc[i][j] = (floatx4){0.f, 0.f, 0.f, 0.f};

    int lrow = lane >> 2;
    int lcg  = (lane & 3) ^ ((lrow >> 1) & 3);
    const u16* Ag = A + (size_t)(row0 + w * 32 + lrow) * DD + lcg * 8;
    const u16* Bg = W + (size_t)(col0 + w * 16 + lrow) * DD + lcg * 8;
    const int NT = DD >> 5;   // 32
    int slot8 = (q ^ ((m >> 1) & 3)) * 8;

    auto stage = [&](int t, int buf) {
        const u16* Aq = Ag + (size_t)t * 32;
        const u16* Bq = Bg + (size_t)t * 32;
        gload_lds16(Aq,                   &As[buf][(w * 32) * 32]);
        gload_lds16(Aq + (size_t)16 * DD, &As[buf][(w * 32 + 16) * 32]);
        gload_lds16(Bq,                   &Bs[buf][(w * 16) * 32]);
    };
    stage(0, 0); stage(1, 1);

    int cur = 0;
    for (int t = 0; t < NT; ++t) {
        if (t + 2 < NT) {
            int nxt = cur + 2; if (nxt >= 3) nxt -= 3;
            stage(t + 2, nxt);
            WAITVM(6);
        } else if (t + 2 == NT) {
            WAITVM(3);
        } else {
            WAITVM(0);
        }
        __builtin_amdgcn_s_barrier();
        CFENCE();
        short8 af[2], bf[4];
        #pragma unroll
        for (int f = 0; f < 2; f++)
            af[f] = *(const short8*)&As[cur][(wm + f * 16 + m) * 32 + slot8];
        #pragma unroll
        for (int f = 0; f < 4; f++)
            bf[f] = *(const short8*)&Bs[cur][(f * 16 + m) * 32 + slot8];
        __builtin_amdgcn_s_setprio(1);
        #pragma unroll
        for (int mf = 0; mf < 2; mf++)
            #pragma unroll
            for (int nf = 0; nf < 4; nf++)
                acc[mf][nf] = __builtin_amdgcn_mfma_f32_16x16x32_bf16(
                    af[mf], bf[nf], acc[mf][nf], 0, 0, 0);
        __builtin_amdgcn_s_setprio(0);
        if (t + 1 < NT) {
            __builtin_amdgcn_s_barrier();
            CFENCE();
        }
        cur = (cur + 1 == 3) ? 0 : cur + 1;
    }

    // ---- fused epilogue ----
    int seg = col0 >> 6;             // 0..15 q, 16..31 k, 32..47 v
    int b   = row0 >> 11;            // batch (uniform per block)
    int mi0 = (row0 & 2047) + wm;

    float b0[4];
    #pragma unroll
    for (int nf = 0; nf < 4; nf++) b0[nf] = bias[col0 + nf * 16 + m];

    if (seg < 32) {
        int hq = seg & 15;
        u16* dst = (seg < 16 ? qb : kb) + (size_t)(b * HH + hq) * MM * DHH;
        #pragma unroll
        for (int mf = 0; mf < 2; mf++) {
            #pragma unroll
            for (int r = 0; r < 4; r++) {
                int mi = mi0 + mf * 16 + q * 4 + r;
                float2 cs0 = tab[mi * 32 + m];        // pair (m, m+32)
                float2 cs1 = tab[mi * 32 + 16 + m];   // pair (16+m, 48+m)
                float a0 = acc[mf][0][r] + b0[0];
                float a1 = acc[mf][1][r] + b0[1];
                float a2 = acc[mf][2][r] + b0[2];
                float a3 = acc[mf][3][r] + b0[3];
                size_t base = (size_t)mi * DHH;
                dst[base + m]      = f2bf(a0 * cs0.x - a2 * cs0.y);
                dst[base + 32 + m] = f2bf(a0 * cs0.y + a2 * cs0.x);
                dst[base + 16 + m] = f2bf(a1 * cs1.x - a3 * cs1.y);
                dst[base + 48 + m] = f2bf(a1 * cs1.y + a3 * cs1.x);
            }
        }
    } else {
        int hv = seg & 15;
        u16* dst = vtb + (size_t)(b * HH + hv) * DHH * MM;
        #pragma unroll
        for (int nf = 0; nf < 4; nf++) {
            int d = nf * 16 + m;
            #pragma unroll
            for (int mf = 0; mf < 2; mf++) {
                int mi = mi0 + mf * 16 + q * 4;
                ushort4v o;
                o.x = f2bf(acc[mf][nf][0] + b0[nf]);
                o.y = f2bf(acc[mf][nf][1] + b0[nf]);
                o.z = f2bf(acc[mf][nf][2] + b0[nf]);
                o.w = f2bf(acc[mf][nf][3] + b0[nf]);
                *(ushort4v*)(dst + (size_t)d * MM + mi) = o;
            }
        }
    }
}

// ---------------- dual-B MLP GEMM (BM=128 x BN=128): gelu(A Wi^T) * (A Wg^T) ------
// m97-class tile: 4 waves 2x2, wave tile dual 64x64, 32 MFMA per barrier-pair.
// Operands via LDS (frag reads transient ~48 VGPR; acc 128 VGPR -> ~190 total,
// 2 waves/SIMD). Depth-2 counted-vmcnt, 3 LDS buffers (72 KB, 2 blocks/CU).
__global__ __launch_bounds__(256, 2)
void mfma_gemm_glu(const u16* __restrict__ A, const u16* __restrict__ W1,
                   const u16* __restrict__ W2, u16* __restrict__ Cout) {
    __shared__ u16 As [3][128 * 32];
    __shared__ u16 B1s[3][128 * 32];
    __shared__ u16 B2s[3][128 * 32];
    int tid = threadIdx.x;
    int w = tid >> 6, lane = tid & 63;
    int q = lane >> 4, m = lane & 15;

    int nbx = gridDim.x;   // FFP/128 = 21
    int id = xcd_swizzle(blockIdx.y * nbx + blockIdx.x, nbx * gridDim.y);
    int bx = id % nbx, by = id / nbx;
    int row0 = by * 128, col0 = bx * 128;
    int wm = (w >> 1) * 64, wn = (w & 1) * 64;

    floatx4 acc1[4][4], acc2[4][4];
    #pragma unroll
    for (int i = 0; i < 4; i++)
        #pragma unroll
        for (int j = 0; j < 4; j++) {
            acc1[i][j] = (floatx4){0.f, 0.f, 0.f, 0.f};
            acc2[i][j] = (floatx4){0.f, 0.f, 0.f, 0.f};
        }

    int lrow = lane >> 2;
    int lcg  = (lane & 3) ^ ((lrow >> 1) & 3);
    const u16* Ag  = A  + (size_t)(row0 + w * 32 + lrow) * DD + lcg * 8;
    const u16* B1g = W1 + (size_t)(col0 + w * 32 + lrow) * DD + lcg * 8;
    const u16* B2g = W2 + (size_t)(col0 + w * 32 + lrow) * DD + lcg * 8;
    const int NT = DD >> 5;   // 32
    int slot8 = (q ^ ((m >> 1) & 3)) * 8;

    auto stage = [&](int t, int buf) {
        const u16* Aq  = Ag  + (size_t)t * 32;
        const u16* B1q = B1g + (size_t)t * 32;
        const u16* B2q = B2g + (size_t)t * 32;
        gload_lds16(Aq,                   &As [buf][(w * 32) * 32]);
        gload_lds16(Aq + (size_t)16 * DD, &As [buf][(w * 32 + 16) * 32]);
        gload_lds16(B1q,                   &B1s[buf][(w * 32) * 32]);
        gload_lds16(B1q + (size_t)16 * DD, &B1s[buf][(w * 32 + 16) * 32]);
        gload_lds16(B2q,                   &B2s[buf][(w * 32) * 32]);
        gload_lds16(B2q + (size_t)16 * DD, &B2s[buf][(w * 32 + 16) * 32]);
    };
    stage(0, 0); stage(1, 1);   // 12 loads/wave outstanding

    int cur = 0;
    for (int t = 0; t < NT; ++t) {
        if (t + 2 < NT) {
            int nxt = cur + 2; if (nxt >= 3) nxt -= 3;
            stage(t + 2, nxt);
            WAITVM(12);         // tile t landed; t+1,t+2 (12 loads) in flight
        } else if (t + 2 == NT) {
            WAITVM(6);
        } else {
            WAITVM(0);
        }
        __builtin_amdgcn_s_barrier();
        CFENCE();
        short8 af[4], b1f[4], b2f[4];
        #pragma unroll
        for (int f = 0; f < 4; f++) {
            af[f]  = *(const short8*)&As [cur][(wm + f * 16 + m) * 32 + slot8];
            b1f[f] = *(const short8*)&B1s[cur][(wn + f * 16 + m) * 32 + slot8];
            b2f[f] = *(const short8*)&B2s[cur][(wn + f * 16 + m) * 32 + slot8];
        }
        __builtin_amdgcn_s_setprio(1);
        #pragma unroll
        for (int mf = 0; mf < 4; mf++)
            #pragma unroll
            for (int nf = 0; nf < 4; nf++) {
                acc1[mf][nf] = __builtin_amdgcn_mfma_f32_16x16x32_bf16(
                    af[mf], b1f[nf], acc1[mf][nf], 0, 0, 0);
                acc2[mf][nf] = __builtin_amdgcn_mfma_f32_16x16x32_bf16(
                    af[mf], b2f[nf], acc2[mf][nf], 0, 0, 0);
            }
        __builtin_amdgcn_s_setprio(0);
        if (t + 1 < NT) {
            __builtin_amdgcn_s_barrier();   // reads of buf[cur] done before restage
            CFENCE();
        }
        cur = (cur + 1 == 3) ? 0 : cur + 1;
    }

    #pragma unroll
    for (int nf = 0; nf < 4; nf++) {
        int col = col0 + wn + nf * 16 + m;
        #pragma unroll
        for (int mf = 0; mf < 4; mf++) {
            #pragma unroll
            for (int r = 0; r < 4; r++) {
                int row = row0 + wm + mf * 16 + q * 4 + r;
                Cout[(size_t)row * FFP + col] =
                    f2bf(gelu_exact(acc1[mf][nf][r]) * acc2[mf][nf][r]);
            }
        }
    }
}

// ---------------- MFMA flash attention, 32x32 swapped-QK^T, in-register softmax ----
// 4 waves x 32 Q-rows (128/block, grid 512). St = mfma(K,Q) -> lane owns Q-row
// (col=lane&31): softmax denominator is one per-lane scalar, P stays in registers.
// K rows sigma-staged (swap bits 2<->3 of LDS row) so St's C-layout regs land in
// PV A-fragment order: pa[s] = p[8s..8s+7] -> 16 cvt_pk, zero cross-lane ops.
__global__ __launch_bounds__(256, 2)
void flash_attn_mfma32(const u16* __restrict__ qp, const u16* __restrict__ kp,
                       const u16* __restrict__ vt, const int* __restrict__ mask,
                       u16* __restrict__ out) {
    __shared__ __align__(16) u16 Ks[2 * 64 * 64];   // [buf][kv(sigma)][chunk swz row&7]
    __shared__ __align__(16) u16 Vs[2 * 64 * 64];   // [buf][d][kv chunk swz row&7]

    int tid = threadIdx.x;
    int w = tid >> 6, lane = tid & 63;
    int col = lane & 31, hi = lane >> 5;
    int mt = blockIdx.x, h = blockIdx.y, b = blockIdx.z;
    int m0 = mt * 128;
    size_t bh = (size_t)(b * HH + h);
    const u16* qg  = qp + (bh * MM + m0 + w * 32) * DHH;
    const u16* kg  = kp + bh * MM * DHH;
    const u16* vtg = vt + bh * DHH * MM;

    // number of valid 64-aligned KV tiles (monotone mask; uniform scalar loads)
    int ntv = 0;
    for (int n = 0; n < MM; n += 64) ntv += (mask[b * MM + n] != 0);

    // Q fragments straight to registers: B-operand Q[qrow=col][k=(2t+hi)*8..+7]
    short8 qf[4];
    #pragma unroll
    for (int t = 0; t < 4; t++)
        qf[t] = *(const short8*)(qg + (size_t)col * DHH + (2 * t + hi) * 8);

    // staging geometry: each gload = 8 LDS rows x 8 chunks; chunk pre-swizzle c^(row&7)
    int lr = lane >> 3, lc = lane & 7;
    int lcg = lc ^ lr;
    int i0 = w * 16 + lr, i1 = i0 + 8;          // this wave's LDS rows
    int sg0 = (i0 & ~12) | ((i0 & 4) << 1) | ((i0 & 8) >> 1);   // sigma(i0)
    int sg1 = (i1 & ~12) | ((i1 & 4) << 1) | ((i1 & 8) >> 1);   // sigma(i1)
    const u16* Kg0 = kg + (size_t)sg0 * DHH + lcg * 8;
    const u16* Kg1 = kg + (size_t)sg1 * DHH + lcg * 8;
    const u16* Vg0 = vtg + (size_t)i0 * MM + lcg * 8;
    const u16* Vg1 = vtg + (size_t)i1 * MM + lcg * 8;
    u16* KL0 = Ks + (w * 16) * 64;
    u16* KL1 = KL0 + 8 * 64;
    u16* VL0 = Vs + (w * 16) * 64;
    u16* VL1 = VL0 + 8 * 64;
    const int BUFO = 64 * 64;   // u16 elements per buffer

    // prologue: stage tile 0 into buf 0 (4 gloads/wave)
    gload_lds16(Kg0, KL0); gload_lds16(Kg1, KL1);
    gload_lds16(Vg0, VL0); gload_lds16(Vg1, VL1);

    floatx16 O0, O1;
    #pragma unroll
    for (int r = 0; r < 16; r++) { O0[r] = 0.f; O1[r] = 0.f; }
    float ls = 0.f;

    int swz = (col & 7) * 8;    // chunk-swizzle term for frag reads

    for (int it = 0; it < ntv; ++it) {
        int cur = it & 1;
        int co = cur * BUFO, po = (cur ^ 1) * BUFO;
        if (it + 1 < ntv) {
            size_t nk = (size_t)(it + 1) * 64;
            gload_lds16(Kg0 + nk * DHH, KL0 + po);
            gload_lds16(Kg1 + nk * DHH, KL1 + po);
            gload_lds16(Vg0 + nk,       VL0 + po);
            gload_lds16(Vg1 + nk,       VL1 + po);
            WAITVM(4);          // current tile landed; next tile in flight
        } else {
            WAITVM(0);
        }
        __builtin_amdgcn_s_barrier();
        CFENCE();

        // ---- St = K(sigma) . Q^T : lane owns Q-row `col`, 16 kv per lane ----
        floatx16 P0, P1;
        #pragma unroll
        for (int r = 0; r < 16; r++) { P0[r] = 0.f; P1[r] = 0.f; }
        #pragma unroll
        for (int t = 0; t < 4; t++) {
            int ck = (((2 * t + hi) * 8) ^ swz);
            short8 kf0 = *(const short8*)&Ks[co + col * 64 + ck];
            short8 kf1 = *(const short8*)&Ks[co + (32 + col) * 64 + ck];
            __builtin_amdgcn_s_setprio(1);
            P0 = __builtin_amdgcn_mfma_f32_32x32x16_bf16(kf0, qf[t], P0, 0, 0, 0);
            P1 = __builtin_amdgcn_mfma_f32_32x32x16_bf16(kf1, qf[t], P1, 0, 0, 0);
            __builtin_amdgcn_s_setprio(0);
        }

        // ---- max-free softmax, in-register; per-lane scalar denominator ----
        #pragma unroll
        for (int r = 0; r < 16; r++) {
            float e0 = exp2f(P0[r] * SCALE2);
            float e1 = exp2f(P1[r] * SCALE2);
            P0[r] = e0; P1[r] = e1;
            ls += e0 + e1;
        }

        // ---- pack P to bf16 A-fragments (sigma makes reg order = frag order) ----
        short8 pa0 = pack8(P0[0], P0[1], P0[2],  P0[3],  P0[4],  P0[5],  P0[6],  P0[7]);
        short8 pa1 = pack8(P0[8], P0[9], P0[10], P0[11], P0[12], P0[13], P0[14], P0[15]);
        short8 pa2 = pack8(P1[0], P1[1], P1[2],  P1[3],  P1[4],  P1[5],  P1[6],  P1[7]);
        short8 pa3 = pack8(P1[8], P1[9], P1[10], P1[11], P1[12], P1[13], P1[14], P1[15]);

        // ---- O += P V  (B-operand Vt[d][kv]) ----
        #pragma unroll
        for (int s = 0; s < 4; s++) {
            int ck = (((2 * s + hi) * 8) ^ swz);
            short8 vf0 = *(const short8*)&Vs[co + col * 64 + ck];
            short8 vf1 = *(const short8*)&Vs[co + (32 + col) * 64 + ck];
            short8 pas = (s == 0) ? pa0 : (s == 1) ? pa1 : (s == 2) ? pa2 : pa3;
            __builtin_amdgcn_s_setprio(1);
            O0 = __builtin_amdgcn_mfma_f32_32x32x16_bf16(pas, vf0, O0, 0, 0, 0);
            O1 = __builtin_amdgcn_mfma_f32_32x32x16_bf16(pas, vf1, O1, 0, 0, 0);
            __builtin_amdgcn_s_setprio(0);
        }
        __builtin_amdgcn_s_barrier();   // buf[cur] reads done before restage
        CFENCE();
    }
    WAITVM(0);      // drain stray prefetch before LDS goes out of scope
    CFENCE();

    // ---- epilogue: denominator = sum over both hi-halves of the Q-row ----
    ls += __shfl_xor(ls, 32);
    float inv = 1.0f / ls;              // valid for qrow = col (both hi lanes)
    float invr[16];
    #pragma unroll
    for (int r = 0; r < 16; r++) {
        int crow = (r & 3) + 8 * (r >> 2) + 4 * hi;   // O-row for this reg
        invr[r] = __shfl(inv, crow, 64);
    }
    u16* ob = out + ((size_t)(b * MM) + m0 + w * 32) * DD + h * DHH;
    #pragma unroll
    for (int r = 0; r < 16; r++) {
        int crow = (r & 3) + 8 * (r >> 2) + 4 * hi;
        ob[(size_t)crow * DD + col]      = f2bf(O0[r] * invr[r]);
        ob[(size_t)crow * DD + 32 + col] = f2bf(O1[r] * invr[r]);
    }
}

extern "C" void kernel_launch(void* const* d_in, const int* in_sizes, int n_in,
                              void* d_out, int out_size, void* d_ws, size_t ws_size,
                              hipStream_t stream) {
    const float* hidden   = (const float*)d_in[0];
    const int*   mask     = (const int*)d_in[1];
    const float* ln1_w    = (const float*)d_in[2];
    const float* ln1_b    = (const float*)d_in[3];
    const float* wqkv_w   = (const float*)d_in[4];
    const float* wqkv_b   = (const float*)d_in[5];
    const float* wo_w     = (const float*)d_in[6];
    const float* ln2_w    = (const float*)d_in[7];
    const float* ln2_b    = (const float*)d_in[8];
    const float* wi_w     = (const float*)d_in[9];
    const float* wo_mlp_w = (const float*)d_in[10];
    float* out = (float*)d_out;

    char* ws = (char*)d_ws;
    u16* wqkv_bf  = (u16*)(ws);                         //  6.00 MB
    u16* wo_bf    = (u16*)(ws + 6291456);               //  2.00 MB
    u16* wi_inp   = (u16*)(ws + 8388608);               //  5.25 MB
    u16* wi_gate  = (u16*)(ws + 13893632);              //  5.25 MB
    u16* womlp_bf = (u16*)(ws + 19398656);              //  5.25 MB
    u16* xn       = (u16*)(ws + 24903680);              //  8 MB [4096][1024]
    float2* rtab  = (float2*)(ws + 33292288);           //  512 KB rope table
    u16* qb       = (u16*)(ws + 58458112);              //  8 MB (B,H,M,DH)
    u16* kb       = (u16*)(ws + 66846720);              //  8 MB
    u16* vtb      = (u16*)(ws + 75235328);              //  8 MB (B,H,DH,M)
    u16* attn_out = (u16*)(ws + 83623936);              //  8 MB
    u16* hb       = (u16*)(ws + 92012544);              //  8 MB
    u16* act      = (u16*)(ws + 58458112);              // 22 MB, reuses qb/kb/vt

    // 0. all weight conversions + rope table (one dispatch)
    cvt_all<<<4096 + 2 * FFP + 1024 + 64, 256, 0, stream>>>(
        wqkv_w, wo_w, wi_w, wo_mlp_w, wqkv_bf, wo_bf, wi_inp, wi_gate, womlp_bf, rtab);
    // 1. LN1
    ln_kernel<<<TT, 256, 0, stream>>>(hidden, ln1_w, ln1_b, xn);
    // 2. fused QKV GEMM + bias + RoPE + V-transpose scatter  (1536 blocks)
    mfma_gemm_qkv<<<dim3(3 * DD / 64, TT / 128), 256, 0, stream>>>(
        xn, wqkv_bf, wqkv_b, rtab, qb, kb, vtb);
    // 3. MFMA flash attention, 32x32 swapped (512 blocks, 128 Q-rows each)
    flash_attn_mfma32<<<dim3(MM / 128, HH, BB), 256, 0, stream>>>(
        qb, kb, vtb, mask, attn_out);
    // 4. x1 = hidden + attn_out @ Wo^T -> d_out (fp32)   (512 blocks)
    mfma_gemm64<1, false><<<dim3(DD / 64, TT / 128), 256, 0, stream>>>(
        attn_out, wo_bf, nullptr, hidden, out, DD, DD);
    // 5. LN2
    ln_kernel<<<TT, 256, 0, stream>>>(out, ln2_w, ln2_b, hb);
    // 6. act = gelu(h@Wi^T) * (h@Wg^T)  BN=128 LDS GEMM (672 blocks, 21x32)
    mfma_gemm_glu<<<dim3(FFP / 128, TT / 128), 256, 0, stream>>>(
        hb, wi_inp, wi_gate, act);
    // 7. out = out + act @ Wo_mlp^T   (512 blocks)
    mfma_gemm64<1, false><<<dim3(DD / 64, TT / 128), 256, 0, stream>>>(
        act, womlp_bf, nullptr, out, out, DD, FFP);
}

// Round 8
// 360.703 us; speedup vs baseline: 1.2193x; 1.0514x over previous
//
#include <hip/hip_runtime.h>
#include <hip/hip_bf16.h>
#include <math.h>

#define BB 2
#define MM 2048
#define DD 1024
#define HH 16
#define DHH 64
#define FF_ 2624
#define FFP 2688            // FF padded to /128
#define TT (BB*MM)          // 4096

typedef unsigned short u16;
typedef __attribute__((ext_vector_type(4))) unsigned short ushort4v;
typedef __attribute__((ext_vector_type(8))) short short8;
typedef __attribute__((ext_vector_type(4))) float floatx4;
typedef __attribute__((ext_vector_type(16))) float floatx16;

#define SCALE2 0.18033688011112043f   // 0.125 * log2(e)

// counted-vmcnt + compiler fences for the raw-barrier pipeline
#define WAITVM(N) asm volatile("s_waitcnt vmcnt(" #N ")" ::: "memory")
#define CFENCE()  asm volatile("" ::: "memory")

__device__ __forceinline__ u16 f2bf(float f) {
    __hip_bfloat16 h = __float2bfloat16(f);
    return *(u16*)&h;
}
__device__ __forceinline__ float bf2f(u16 u) {
    __hip_bfloat16 h; *(u16*)&h = u;
    return __bfloat162float(h);
}
__device__ __forceinline__ float gelu_exact(float x) {
    return 0.5f * x * (1.0f + erff(x * 0.70710678118654752f));
}
__device__ __forceinline__ void gload_lds16(const void* g, void* l) {
    __builtin_amdgcn_global_load_lds(
        (const __attribute__((address_space(1))) unsigned int*)g,
        (__attribute__((address_space(3))) unsigned int*)l, 16, 0, 0);
}
__device__ __forceinline__ unsigned int cvt_pk_bf16(float a, float b) {
    unsigned int r;
    asm("v_cvt_pk_bf16_f32 %0, %1, %2" : "=v"(r) : "v"(a), "v"(b));
    return r;
}
__device__ __forceinline__ short8 pack8(float a0, float a1, float a2, float a3,
                                        float a4, float a5, float a6, float a7) {
    union { unsigned int u[4]; short8 s; } r;
    r.u[0] = cvt_pk_bf16(a0, a1); r.u[1] = cvt_pk_bf16(a2, a3);
    r.u[2] = cvt_pk_bf16(a4, a5); r.u[3] = cvt_pk_bf16(a6, a7);
    return r.s;
}

// bijective XCD swizzle (grid counts all divisible by 8 here; guarded anyway)
__device__ __forceinline__ int xcd_swizzle(int id, int nb) {
    if (nb & 7) return id;
    return (id & 7) * (nb >> 3) + (id >> 3);
}

// ---------------- fused weight conversion + rope table (one dispatch) -------------
__global__ void cvt_all(const float* __restrict__ wqkv, const float* __restrict__ wo,
                        const float* __restrict__ wi, const float* __restrict__ womlp,
                        u16* __restrict__ dqkv, u16* __restrict__ dwo,
                        u16* __restrict__ dinp, u16* __restrict__ dgate,
                        u16* __restrict__ dmlp, float2* __restrict__ tab) {
    int bid = blockIdx.x, tid = threadIdx.x;
    if (bid < 3072) {
        int i = (bid * 256 + tid) * 4;
        float4 v = *(const float4*)(wqkv + i);
        ushort4v o = {f2bf(v.x), f2bf(v.y), f2bf(v.z), f2bf(v.w)};
        *(ushort4v*)(dqkv + i) = o;
    } else if (bid < 4096) {
        int i = ((bid - 3072) * 256 + tid) * 4;
        float4 v = *(const float4*)(wo + i);
        ushort4v o = {f2bf(v.x), f2bf(v.y), f2bf(v.z), f2bf(v.w)};
        *(ushort4v*)(dwo + i) = o;
    } else if (bid < 4096 + 2 * FFP) {
        int seg = (bid - 4096) / FFP;          // 0: inp, 1: gate
        int row = (bid - 4096) % FFP;
        u16* dst = seg ? dgate : dinp;
        const float* src = wi + (size_t)(seg ? FF_ : 0) * DD;
        int c = tid * 4;
        ushort4v o = {0, 0, 0, 0};
        if (row < FF_) {
            float4 v = *(const float4*)(src + (size_t)row * DD + c);
            o.x = f2bf(v.x); o.y = f2bf(v.y); o.z = f2bf(v.z); o.w = f2bf(v.w);
        }
        *(ushort4v*)(dst + (size_t)row * DD + c) = o;
    } else if (bid < 4096 + 2 * FFP + 1024) {
        int row = bid - 4096 - 2 * FFP;        // 0..1023
        for (int c = tid * 4; c < FFP; c += 1024) {
            ushort4v o = {0, 0, 0, 0};
            if (c < FF_) {
                float4 v = *(const float4*)(womlp + (size_t)row * FF_ + c);
                o.x = f2bf(v.x); o.y = f2bf(v.y); o.z = f2bf(v.z); o.w = f2bf(v.w);
            }
            *(ushort4v*)(dmlp + (size_t)row * FFP + c) = o;
        }
    } else {
        // rope table: tab[mi*32 + i] = (cos, sin) of mi * 10000^(-i/32)
        int bq = bid - (4096 + 2 * FFP + 1024);   // 0..63
        int base = bq * 1024;
        for (int idx = tid; idx < 1024; idx += 256) {
            int e = base + idx;
            int mi = e >> 5, i = e & 31;
            float fr = (float)mi * powf(10000.0f, -(float)i / 32.0f);
            tab[e] = make_float2(cosf(fr), sinf(fr));
        }
    }
}

// ---------------- LayerNorm: fp32 in -> bf16 out ----------------------------------
__global__ void ln_kernel(const float* __restrict__ x, const float* __restrict__ w,
                          const float* __restrict__ b, u16* __restrict__ out) {
    int row = blockIdx.x;
    int tid = threadIdx.x;
    const float4 v = ((const float4*)(x + (size_t)row * DD))[tid];
    float s  = v.x + v.y + v.z + v.w;
    float ss = v.x*v.x + v.y*v.y + v.z*v.z + v.w*v.w;
    #pragma unroll
    for (int o = 32; o > 0; o >>= 1) { s += __shfl_down(s, o); ss += __shfl_down(ss, o); }
    __shared__ float sbuf[4], ssbuf[4];
    int wid = tid >> 6;
    if ((tid & 63) == 0) { sbuf[wid] = s; ssbuf[wid] = ss; }
    __syncthreads();
    float st  = sbuf[0] + sbuf[1] + sbuf[2] + sbuf[3];
    float sst = ssbuf[0] + ssbuf[1] + ssbuf[2] + ssbuf[3];
    float mean = st * (1.0f / DD);
    float var  = sst * (1.0f / DD) - mean * mean;
    float rstd = rsqrtf(var + 1e-5f);
    const float4 wv = ((const float4*)w)[tid];
    const float4 bv = ((const float4*)b)[tid];
    ushort4v o;
    o.x = f2bf((v.x - mean) * rstd * wv.x + bv.x);
    o.y = f2bf((v.y - mean) * rstd * wv.y + bv.y);
    o.z = f2bf((v.z - mean) * rstd * wv.z + bv.z);
    o.w = f2bf((v.w - mean) * rstd * wv.w + bv.w);
    ((ushort4v*)(out + (size_t)row * DD))[tid] = o;
}

// =============== depth-2 counted-vmcnt GEMM core (BK=32, 3 LDS buffers) ===========

// ---------------- std GEMM, BM=128 x BN=64: C = A[TxK] * W[NxK]^T -----------------
// MODE 0: +bias(optional fp32)   MODE 1: +add(fp32), fp32 out
template<int MODE, bool OUT_BF16>
__global__ __launch_bounds__(256, 4)
void mfma_gemm64(const u16* __restrict__ A, const u16* __restrict__ W,
                 const float* __restrict__ bias, const void* __restrict__ add,
                 void* __restrict__ Cout, int N, int K) {
    __shared__ u16 As[3][128 * 32];
    __shared__ u16 Bs[3][64 * 32];
    int tid = threadIdx.x;
    int w = tid >> 6, lane = tid & 63;
    int q = lane >> 4, m = lane & 15;

    int nbx = gridDim.x;
    int id = xcd_swizzle(blockIdx.y * nbx + blockIdx.x, nbx * gridDim.y);
    int bx = id % nbx, by = id / nbx;
    int row0 = by * 128, col0 = bx * 64;
    int wm = (w >> 1) * 64, wn = (w & 1) * 32;

    floatx4 acc[4][2];
    #pragma unroll
    for (int i = 0; i < 4; i++)
        #pragma unroll
        for (int j = 0; j < 2; j++)
            acc[i][j] = (floatx4){0.f, 0.f, 0.f, 0.f};

    int lrow = lane >> 2;
    int lcg  = (lane & 3) ^ ((lrow >> 1) & 3);
    const u16* Ag = A + (size_t)(row0 + w * 32 + lrow) * K + lcg * 8;
    const u16* Bg = W + (size_t)(col0 + w * 16 + lrow) * K + lcg * 8;
    int NT = K >> 5;
    int slot8 = (q ^ ((m >> 1) & 3)) * 8;

    auto stage = [&](int t, int buf) {
        const u16* Aq = Ag + (size_t)t * 32;
        const u16* Bq = Bg + (size_t)t * 32;
        gload_lds16(Aq,                  &As[buf][(w * 32) * 32]);
        gload_lds16(Aq + (size_t)16 * K, &As[buf][(w * 32 + 16) * 32]);
        gload_lds16(Bq,                  &Bs[buf][(w * 16) * 32]);
    };
    stage(0, 0); stage(1, 1);   // 6 loads/wave outstanding

    int cur = 0;
    for (int t = 0; t < NT; ++t) {
        if (t + 2 < NT) {
            int nxt = cur + 2; if (nxt >= 3) nxt -= 3;
            stage(t + 2, nxt);
            WAITVM(6);          // tile t landed; t+1,t+2 in flight
        } else if (t + 2 == NT) {
            WAITVM(3);
        } else {
            WAITVM(0);
        }
        __builtin_amdgcn_s_barrier();
        CFENCE();
        short8 af[4], bf[2];
        #pragma unroll
        for (int f = 0; f < 4; f++)
            af[f] = *(const short8*)&As[cur][(wm + f * 16 + m) * 32 + slot8];
        #pragma unroll
        for (int f = 0; f < 2; f++)
            bf[f] = *(const short8*)&Bs[cur][(wn + f * 16 + m) * 32 + slot8];
        __builtin_amdgcn_s_setprio(1);
        #pragma unroll
        for (int mf = 0; mf < 4; mf++)
            #pragma unroll
            for (int nf = 0; nf < 2; nf++)
                acc[mf][nf] = __builtin_amdgcn_mfma_f32_16x16x32_bf16(
                    af[mf], bf[nf], acc[mf][nf], 0, 0, 0);
        __builtin_amdgcn_s_setprio(0);
        if (t + 1 < NT) {
            __builtin_amdgcn_s_barrier();   // reads of buf[cur] done before restage
            CFENCE();
        }
        cur = (cur + 1 == 3) ? 0 : cur + 1;
    }

    #pragma unroll
    for (int nf = 0; nf < 2; nf++) {
        int col = col0 + wn + nf * 16 + m;
        float bv = 0.f;
        if (MODE == 0 && bias) bv = bias[col];
        #pragma unroll
        for (int mf = 0; mf < 4; mf++) {
            #pragma unroll
            for (int r = 0; r < 4; r++) {
                int row = row0 + wm + mf * 16 + q * 4 + r;
                size_t idx = (size_t)row * N + col;
                float vacc = acc[mf][nf][r] + bv;
                if (MODE == 1) vacc += ((const float*)add)[idx];
                if (OUT_BF16) ((u16*)Cout)[idx] = f2bf(vacc);
                else          ((float*)Cout)[idx] = vacc;
            }
        }
    }
}

// ---------------- fused QKV GEMM (BM=128 x BN=64) + bias + RoPE + scatter ---------
__global__ __launch_bounds__(256, 4)
void mfma_gemm_qkv(const u16* __restrict__ A, const u16* __restrict__ W,
                   const float* __restrict__ bias, const float2* __restrict__ tab,
                   u16* __restrict__ qb, u16* __restrict__ kb, u16* __restrict__ vtb) {
    __shared__ u16 As[3][128 * 32];
    __shared__ u16 Bs[3][64 * 32];
    int tid = threadIdx.x;
    int w = tid >> 6, lane = tid & 63;
    int q = lane >> 4, m = lane & 15;

    int nbx = gridDim.x;
    int id = xcd_swizzle(blockIdx.y * nbx + blockIdx.x, nbx * gridDim.y);
    int bx = id % nbx, by = id / nbx;
    int row0 = by * 128, col0 = bx * 64;
    int wm = w * 32;

    floatx4 acc[2][4];
    #pragma unroll
    for (int i = 0; i < 2; i++)
        #pragma unroll
        for (int j = 0; j < 4; j++)
            acc[i][j] = (floatx4){0.f, 0.f, 0.f, 0.f};

    int lrow = lane >> 2;
    int lcg  = (lane & 3) ^ ((lrow >> 1) & 3);
    const u16* Ag = A + (size_t)(row0 + w * 32 + lrow) * DD + lcg * 8;
    const u16* Bg = W + (size_t)(col0 + w * 16 + lrow) * DD + lcg * 8;
    const int NT = DD >> 5;   // 32
    int slot8 = (q ^ ((m >> 1) & 3)) * 8;

    auto stage = [&](int t, int buf) {
        const u16* Aq = Ag + (size_t)t * 32;
        const u16* Bq = Bg + (size_t)t * 32;
        gload_lds16(Aq,                   &As[buf][(w * 32) * 32]);
        gload_lds16(Aq + (size_t)16 * DD, &As[buf][(w * 32 + 16) * 32]);
        gload_lds16(Bq,                   &Bs[buf][(w * 16) * 32]);
    };
    stage(0, 0); stage(1, 1);

    int cur = 0;
    for (int t = 0; t < NT; ++t) {
        if (t + 2 < NT) {
            int nxt = cur + 2; if (nxt >= 3) nxt -= 3;
            stage(t + 2, nxt);
            WAITVM(6);
        } else if (t + 2 == NT) {
            WAITVM(3);
        } else {
            WAITVM(0);
        }
        __builtin_amdgcn_s_barrier();
        CFENCE();
        short8 af[2], bf[4];
        #pragma unroll
        for (int f = 0; f < 2; f++)
            af[f] = *(const short8*)&As[cur][(wm + f * 16 + m) * 32 + slot8];
        #pragma unroll
        for (int f = 0; f < 4; f++)
            bf[f] = *(const short8*)&Bs[cur][(f * 16 + m) * 32 + slot8];
        __builtin_amdgcn_s_setprio(1);
        #pragma unroll
        for (int mf = 0; mf < 2; mf++)
            #pragma unroll
            for (int nf = 0; nf < 4; nf++)
                acc[mf][nf] = __builtin_amdgcn_mfma_f32_16x16x32_bf16(
                    af[mf], bf[nf], acc[mf][nf], 0, 0, 0);
        __builtin_amdgcn_s_setprio(0);
        if (t + 1 < NT) {
            __builtin_amdgcn_s_barrier();
            CFENCE();
        }
        cur = (cur + 1 == 3) ? 0 : cur + 1;
    }

    // ---- fused epilogue ----
    int seg = col0 >> 6;             // 0..15 q, 16..31 k, 32..47 v
    int b   = row0 >> 11;            // batch (uniform per block)
    int mi0 = (row0 & 2047) + wm;

    float b0[4];
    #pragma unroll
    for (int nf = 0; nf < 4; nf++) b0[nf] = bias[col0 + nf * 16 + m];

    if (seg < 32) {
        int hq = seg & 15;
        u16* dst = (seg < 16 ? qb : kb) + (size_t)(b * HH + hq) * MM * DHH;
        #pragma unroll
        for (int mf = 0; mf < 2; mf++) {
            #pragma unroll
            for (int r = 0; r < 4; r++) {
                int mi = mi0 + mf * 16 + q * 4 + r;
                float2 cs0 = tab[mi * 32 + m];        // pair (m, m+32)
                float2 cs1 = tab[mi * 32 + 16 + m];   // pair (16+m, 48+m)
                float a0 = acc[mf][0][r] + b0[0];
                float a1 = acc[mf][1][r] + b0[1];
                float a2 = acc[mf][2][r] + b0[2];
                float a3 = acc[mf][3][r] + b0[3];
                size_t base = (size_t)mi * DHH;
                dst[base + m]      = f2bf(a0 * cs0.x - a2 * cs0.y);
                dst[base + 32 + m] = f2bf(a0 * cs0.y + a2 * cs0.x);
                dst[base + 16 + m] = f2bf(a1 * cs1.x - a3 * cs1.y);
                dst[base + 48 + m] = f2bf(a1 * cs1.y + a3 * cs1.x);
            }
        }
    } else {
        int hv = seg & 15;
        u16* dst = vtb + (size_t)(b * HH + hv) * DHH * MM;
        #pragma unroll
        for (int nf = 0; nf < 4; nf++) {
            int d = nf * 16 + m;
            #pragma unroll
            for (int mf = 0; mf < 2; mf++) {
                int mi = mi0 + mf * 16 + q * 4;
                ushort4v o;
                o.x = f2bf(acc[mf][nf][0] + b0[nf]);
                o.y = f2bf(acc[mf][nf][1] + b0[nf]);
                o.z = f2bf(acc[mf][nf][2] + b0[nf]);
                o.w = f2bf(acc[mf][nf][3] + b0[nf]);
                *(ushort4v*)(dst + (size_t)d * MM + mi) = o;
            }
        }
    }
}

// ---------------- dual-B MLP GEMM (BM=128 x BN=64): gelu(A Wi^T) * (A Wg^T) -------
__global__ __launch_bounds__(256, 3)
void mfma_gemm_glu(const u16* __restrict__ A, const u16* __restrict__ W1,
                   const u16* __restrict__ W2, u16* __restrict__ Cout) {
    __shared__ u16 As [3][128 * 32];
    __shared__ u16 B1s[3][64 * 32];
    __shared__ u16 B2s[3][64 * 32];
    int tid = threadIdx.x;
    int w = tid >> 6, lane = tid & 63;
    int q = lane >> 4, m = lane & 15;

    int nbx = gridDim.x;
    int id = xcd_swizzle(blockIdx.y * nbx + blockIdx.x, nbx * gridDim.y);
    int bx = id % nbx, by = id / nbx;
    int row0 = by * 128, col0 = bx * 64;
    int wm = (w >> 1) * 64, wn = (w & 1) * 32;

    floatx4 acc1[4][2], acc2[4][2];
    #pragma unroll
    for (int i = 0; i < 4; i++)
        #pragma unroll
        for (int j = 0; j < 2; j++) {
            acc1[i][j] = (floatx4){0.f, 0.f, 0.f, 0.f};
            acc2[i][j] = (floatx4){0.f, 0.f, 0.f, 0.f};
        }

    int lrow = lane >> 2;
    int lcg  = (lane & 3) ^ ((lrow >> 1) & 3);
    const u16* Ag  = A  + (size_t)(row0 + w * 32 + lrow) * DD + lcg * 8;
    const u16* B1g = W1 + (size_t)(col0 + w * 16 + lrow) * DD + lcg * 8;
    const u16* B2g = W2 + (size_t)(col0 + w * 16 + lrow) * DD + lcg * 8;
    const int NT = DD >> 5;   // 32
    int slot8 = (q ^ ((m >> 1) & 3)) * 8;

    auto stage = [&](int t, int buf) {
        const u16* Aq  = Ag  + (size_t)t * 32;
        const u16* B1q = B1g + (size_t)t * 32;
        const u16* B2q = B2g + (size_t)t * 32;
        gload_lds16(Aq,                   &As [buf][(w * 32) * 32]);
        gload_lds16(Aq + (size_t)16 * DD, &As [buf][(w * 32 + 16) * 32]);
        gload_lds16(B1q,                  &B1s[buf][(w * 16) * 32]);
        gload_lds16(B2q,                  &B2s[buf][(w * 16) * 32]);
    };
    stage(0, 0); stage(1, 1);   // 8 loads/wave outstanding

    int cur = 0;
    for (int t = 0; t < NT; ++t) {
        if (t + 2 < NT) {
            int nxt = cur + 2; if (nxt >= 3) nxt -= 3;
            stage(t + 2, nxt);
            WAITVM(8);          // tile t landed; t+1,t+2 (8 loads) in flight
        } else if (t + 2 == NT) {
            WAITVM(4);
        } else {
            WAITVM(0);
        }
        __builtin_amdgcn_s_barrier();
        CFENCE();
        short8 af[4], b1f[2], b2f[2];
        #pragma unroll
        for (int f = 0; f < 4; f++)
            af[f] = *(const short8*)&As[cur][(wm + f * 16 + m) * 32 + slot8];
        #pragma unroll
        for (int f = 0; f < 2; f++) {
            b1f[f] = *(const short8*)&B1s[cur][(wn + f * 16 + m) * 32 + slot8];
            b2f[f] = *(const short8*)&B2s[cur][(wn + f * 16 + m) * 32 + slot8];
        }
        __builtin_amdgcn_s_setprio(1);
        #pragma unroll
        for (int mf = 0; mf < 4; mf++)
            #pragma unroll
            for (int nf = 0; nf < 2; nf++) {
                acc1[mf][nf] = __builtin_amdgcn_mfma_f32_16x16x32_bf16(
                    af[mf], b1f[nf], acc1[mf][nf], 0, 0, 0);
                acc2[mf][nf] = __builtin_amdgcn_mfma_f32_16x16x32_bf16(
                    af[mf], b2f[nf], acc2[mf][nf], 0, 0, 0);
            }
        __builtin_amdgcn_s_setprio(0);
        if (t + 1 < NT) {
            __builtin_amdgcn_s_barrier();
            CFENCE();
        }
        cur = (cur + 1 == 3) ? 0 : cur + 1;
    }

    #pragma unroll
    for (int nf = 0; nf < 2; nf++) {
        int col = col0 + wn + nf * 16 + m;
        #pragma unroll
        for (int mf = 0; mf < 4; mf++) {
            #pragma unroll
            for (int r = 0; r < 4; r++) {
                int row = row0 + wm + mf * 16 + q * 4 + r;
                Cout[(size_t)row * FFP + col] =
                    f2bf(gelu_exact(acc1[mf][nf][r]) * acc2[mf][nf][r]);
            }
        }
    }
}

// ---------------- MFMA flash attention, 32x32 swapped-QK^T, paired KV tiles --------
// 4 waves x 32 Q-rows (128/block, grid 512). St = mfma(K,Q) -> lane owns Q-row
// (col=lane&31); P stays in registers (sigma-staged K: reg order = PV frag order).
// NEW: KV tiles processed in PAIRS -- 4 LDS buffers (64 KB), 2-tile prefetch with
// vmcnt(8) ladder, ONE barrier-pair per 128 KV (halves sync overhead on the
// serial chain). Per-tile compute body verbatim from the R5-verified kernel.
__global__ __launch_bounds__(256, 2)
void flash_attn_mfma32(const u16* __restrict__ qp, const u16* __restrict__ kp,
                       const u16* __restrict__ vt, const int* __restrict__ mask,
                       u16* __restrict__ out) {
    __shared__ __align__(16) u16 Ks[4 * 64 * 64];   // [buf][kv(sigma)][chunk swz row&7]
    __shared__ __align__(16) u16 Vs[4 * 64 * 64];   // [buf][d][kv chunk swz row&7]

    int tid = threadIdx.x;
    int w = tid >> 6, lane = tid & 63;
    int col = lane & 31, hi = lane >> 5;
    int mt = blockIdx.x, h = blockIdx.y, b = blockIdx.z;
    int m0 = mt * 128;
    size_t bh = (size_t)(b * HH + h);
    const u16* qg  = qp + (bh * MM + m0 + w * 32) * DHH;
    const u16* kg  = kp + bh * MM * DHH;
    const u16* vtg = vt + bh * DHH * MM;

    // number of valid 64-aligned KV tiles (monotone mask; uniform scalar loads)
    int ntv = 0;
    for (int n = 0; n < MM; n += 64) ntv += (mask[b * MM + n] != 0);

    // Q fragments straight to registers: B-operand Q[qrow=col][k=(2t+hi)*8..+7]
    short8 qf[4];
    #pragma unroll
    for (int t = 0; t < 4; t++)
        qf[t] = *(const short8*)(qg + (size_t)col * DHH + (2 * t + hi) * 8);

    // staging geometry: each gload = 8 LDS rows x 8 chunks; chunk pre-swizzle c^(row&7)
    int lr = lane >> 3, lc = lane & 7;
    int lcg = lc ^ lr;
    int i0 = w * 16 + lr, i1 = i0 + 8;          // this wave's LDS rows
    int sg0 = (i0 & ~12) | ((i0 & 4) << 1) | ((i0 & 8) >> 1);   // sigma(i0)
    int sg1 = (i1 & ~12) | ((i1 & 4) << 1) | ((i1 & 8) >> 1);   // sigma(i1)
    const u16* Kg0 = kg + (size_t)sg0 * DHH + lcg * 8;
    const u16* Kg1 = kg + (size_t)sg1 * DHH + lcg * 8;
    const u16* Vg0 = vtg + (size_t)i0 * MM + lcg * 8;
    const u16* Vg1 = vtg + (size_t)i1 * MM + lcg * 8;
    u16* KL0 = Ks + (w * 16) * 64;
    u16* KL1 = KL0 + 8 * 64;
    u16* VL0 = Vs + (w * 16) * 64;
    u16* VL1 = VL0 + 8 * 64;
    const int BUFO = 64 * 64;   // u16 elements per buffer

    auto stage_tile = [&](int t, int buf) {   // 4 gloads/wave
        size_t nk = (size_t)t * 64;
        int o = buf * BUFO;
        gload_lds16(Kg0 + nk * DHH, KL0 + o);
        gload_lds16(Kg1 + nk * DHH, KL1 + o);
        gload_lds16(Vg0 + nk,       VL0 + o);
        gload_lds16(Vg1 + nk,       VL1 + o);
    };

    floatx16 O0, O1;
    #pragma unroll
    for (int r = 0; r < 16; r++) { O0[r] = 0.f; O1[r] = 0.f; }
    float ls = 0.f;

    int swz = (col & 7) * 8;    // chunk-swizzle term for frag reads

    auto compute_tile = [&](int co) {
        // ---- St = K(sigma) . Q^T : lane owns Q-row `col`, 16 kv per lane ----
        floatx16 P0, P1;
        #pragma unroll
        for (int r = 0; r < 16; r++) { P0[r] = 0.f; P1[r] = 0.f; }
        #pragma unroll
        for (int t = 0; t < 4; t++) {
            int ck = (((2 * t + hi) * 8) ^ swz);
            short8 kf0 = *(const short8*)&Ks[co + col * 64 + ck];
            short8 kf1 = *(const short8*)&Ks[co + (32 + col) * 64 + ck];
            __builtin_amdgcn_s_setprio(1);
            P0 = __builtin_amdgcn_mfma_f32_32x32x16_bf16(kf0, qf[t], P0, 0, 0, 0);
            P1 = __builtin_amdgcn_mfma_f32_32x32x16_bf16(kf1, qf[t], P1, 0, 0, 0);
            __builtin_amdgcn_s_setprio(0);
        }
        // ---- max-free softmax, in-register; per-lane scalar denominator ----
        #pragma unroll
        for (int r = 0; r < 16; r++) {
            float e0 = exp2f(P0[r] * SCALE2);
            float e1 = exp2f(P1[r] * SCALE2);
            P0[r] = e0; P1[r] = e1;
            ls += e0 + e1;
        }
        // ---- pack P to bf16 A-fragments (sigma makes reg order = frag order) ----
        short8 pa0 = pack8(P0[0], P0[1], P0[2],  P0[3],  P0[4],  P0[5],  P0[6],  P0[7]);
        short8 pa1 = pack8(P0[8], P0[9], P0[10], P0[11], P0[12], P0[13], P0[14], P0[15]);
        short8 pa2 = pack8(P1[0], P1[1], P1[2],  P1[3],  P1[4],  P1[5],  P1[6],  P1[7]);
        short8 pa3 = pack8(P1[8], P1[9], P1[10], P1[11], P1[12], P1[13], P1[14], P1[15]);
        // ---- O += P V  (B-operand Vt[d][kv]) ----
        #pragma unroll
        for (int s = 0; s < 4; s++) {
            int ck = (((2 * s + hi) * 8) ^ swz);
            short8 vf0 = *(const short8*)&Vs[co + col * 64 + ck];
            short8 vf1 = *(const short8*)&Vs[co + (32 + col) * 64 + ck];
            short8 pas = (s == 0) ? pa0 : (s == 1) ? pa1 : (s == 2) ? pa2 : pa3;
            __builtin_amdgcn_s_setprio(1);
            O0 = __builtin_amdgcn_mfma_f32_32x32x16_bf16(pas, vf0, O0, 0, 0, 0);
            O1 = __builtin_amdgcn_mfma_f32_32x32x16_bf16(pas, vf1, O1, 0, 0, 0);
            __builtin_amdgcn_s_setprio(0);
        }
    };

    // prologue: stage tiles 0,1 into bufs 0,1 (8 gloads/wave; safe even if ntv<2 --
    // kb/vtb rows 64..127 always exist, values simply unused)
    stage_tile(0, 0);
    stage_tile(1, 1);

    int base = 0;
    for (; base + 1 < ntv; base += 2) {
        int pre = ntv - (base + 2);
        if (pre >= 2) {
            stage_tile(base + 2, (base + 2) & 3);
            stage_tile(base + 3, (base + 3) & 3);
            WAITVM(8);          // tiles base,base+1 landed; 8 newest in flight
        } else if (pre == 1) {
            stage_tile(base + 2, (base + 2) & 3);
            WAITVM(4);
        } else {
            WAITVM(0);
        }
        __builtin_amdgcn_s_barrier();
        CFENCE();
        compute_tile((base & 3) * BUFO);
        compute_tile(((base + 1) & 3) * BUFO);
        if (base + 3 < ntv) {   // next super-iter will restage these bufs
            __builtin_amdgcn_s_barrier();
            CFENCE();
        }
    }
    if (base < ntv) {           // odd tail: tile ntv-1 (already staged)
        WAITVM(0);
        __builtin_amdgcn_s_barrier();
        CFENCE();
        compute_tile((base & 3) * BUFO);
    }
    WAITVM(0);      // drain stray prefetch before LDS goes out of scope
    CFENCE();

    // ---- epilogue: denominator = sum over both hi-halves of the Q-row ----
    ls += __shfl_xor(ls, 32);
    float inv = 1.0f / ls;              // valid for qrow = col (both hi lanes)
    float invr[16];
    #pragma unroll
    for (int r = 0; r < 16; r++) {
        int crow = (r & 3) + 8 * (r >> 2) + 4 * hi;   // O-row for this reg
        invr[r] = __shfl(inv, crow, 64);
    }
    u16* ob = out + ((size_t)(b * MM) + m0 + w * 32) * DD + h * DHH;
    #pragma unroll
    for (int r = 0; r < 16; r++) {
        int crow = (r & 3) + 8 * (r >> 2) + 4 * hi;
        ob[(size_t)crow * DD + col]      = f2bf(O0[r] * invr[r]);
        ob[(size_t)crow * DD + 32 + col] = f2bf(O1[r] * invr[r]);
    }
}

extern "C" void kernel_launch(void* const* d_in, const int* in_sizes, int n_in,
                              void* d_out, int out_size, void* d_ws, size_t ws_size,
                              hipStream_t stream) {
    const float* hidden   = (const float*)d_in[0];
    const int*   mask     = (const int*)d_in[1];
    const float* ln1_w    = (const float*)d_in[2];
    const float* ln1_b    = (const float*)d_in[3];
    const float* wqkv_w   = (const float*)d_in[4];
    const float* wqkv_b   = (const float*)d_in[5];
    const float* wo_w     = (const float*)d_in[6];
    const float* ln2_w    = (const float*)d_in[7];
    const float* ln2_b    = (const float*)d_in[8];
    const float* wi_w     = (const float*)d_in[9];
    const float* wo_mlp_w = (const float*)d_in[10];
    float* out = (float*)d_out;

    char* ws = (char*)d_ws;
    u16* wqkv_bf  = (u16*)(ws);                         //  6.00 MB
    u16* wo_bf    = (u16*)(ws + 6291456);               //  2.00 MB
    u16* wi_inp   = (u16*)(ws + 8388608);               //  5.25 MB
    u16* wi_gate  = (u16*)(ws + 13893632);              //  5.25 MB
    u16* womlp_bf = (u16*)(ws + 19398656);              //  5.25 MB
    u16* xn       = (u16*)(ws + 24903680);              //  8 MB [4096][1024]
    float2* rtab  = (float2*)(ws + 33292288);           //  512 KB rope table
    u16* qb       = (u16*)(ws + 58458112);              //  8 MB (B,H,M,DH)
    u16* kb       = (u16*)(ws + 66846720);              //  8 MB
    u16* vtb      = (u16*)(ws + 75235328);              //  8 MB (B,H,DH,M)
    u16* attn_out = (u16*)(ws + 83623936);              //  8 MB
    u16* hb       = (u16*)(ws + 92012544);              //  8 MB
    u16* act      = (u16*)(ws + 58458112);              // 22 MB, reuses qb/kb/vt

    // 0. all weight conversions + rope table (one dispatch)
    cvt_all<<<4096 + 2 * FFP + 1024 + 64, 256, 0, stream>>>(
        wqkv_w, wo_w, wi_w, wo_mlp_w, wqkv_bf, wo_bf, wi_inp, wi_gate, womlp_bf, rtab);
    // 1. LN1
    ln_kernel<<<TT, 256, 0, stream>>>(hidden, ln1_w, ln1_b, xn);
    // 2. fused QKV GEMM + bias + RoPE + V-transpose scatter  (1536 blocks)
    mfma_gemm_qkv<<<dim3(3 * DD / 64, TT / 128), 256, 0, stream>>>(
        xn, wqkv_bf, wqkv_b, rtab, qb, kb, vtb);
    // 3. MFMA flash attention, 32x32 swapped, paired KV tiles (512 blocks)
    flash_attn_mfma32<<<dim3(MM / 128, HH, BB), 256, 0, stream>>>(
        qb, kb, vtb, mask, attn_out);
    // 4. x1 = hidden + attn_out @ Wo^T -> d_out (fp32)   (512 blocks)
    mfma_gemm64<1, false><<<dim3(DD / 64, TT / 128), 256, 0, stream>>>(
        attn_out, wo_bf, nullptr, hidden, out, DD, DD);
    // 5. LN2
    ln_kernel<<<TT, 256, 0, stream>>>(out, ln2_w, ln2_b, hb);
    // 6. act = gelu(h@Wi^T) * (h@Wg^T)  BN=64 LDS GEMM (1344 blocks) -- R5 optimum
    mfma_gemm_glu<<<dim3(FFP / 64, TT / 128), 256, 0, stream>>>(
        hb, wi_inp, wi_gate, act);
    // 7. out = out + act @ Wo_mlp^T   (512 blocks)
    mfma_gemm64<1, false><<<dim3(DD / 64, TT / 128), 256, 0, stream>>>(
        act, womlp_bf, nullptr, out, out, DD, FFP);
}

// Round 9
// 358.657 us; speedup vs baseline: 1.2263x; 1.0057x over previous
//
#include <hip/hip_runtime.h>
#include <hip/hip_bf16.h>
#include <math.h>

#define BB 2
#define MM 2048
#define DD 1024
#define HH 16
#define DHH 64
#define FF_ 2624
#define FFP 2688            // FF padded to /128
#define TT (BB*MM)          // 4096

typedef unsigned short u16;
typedef __attribute__((ext_vector_type(4))) unsigned short ushort4v;
typedef __attribute__((ext_vector_type(8))) short short8;
typedef __attribute__((ext_vector_type(4))) float floatx4;
typedef __attribute__((ext_vector_type(16))) float floatx16;

#define SCALE2 0.18033688011112043f   // 0.125 * log2(e)

// counted-vmcnt + compiler fences for the raw-barrier pipeline
#define WAITVM(N) asm volatile("s_waitcnt vmcnt(" #N ")" ::: "memory")
#define CFENCE()  asm volatile("" ::: "memory")

__device__ __forceinline__ u16 f2bf(float f) {
    __hip_bfloat16 h = __float2bfloat16(f);
    return *(u16*)&h;
}
__device__ __forceinline__ float bf2f(u16 u) {
    __hip_bfloat16 h; *(u16*)&h = u;
    return __bfloat162float(h);
}
__device__ __forceinline__ float gelu_exact(float x) {
    return 0.5f * x * (1.0f + erff(x * 0.70710678118654752f));
}
__device__ __forceinline__ void gload_lds16(const void* g, void* l) {
    __builtin_amdgcn_global_load_lds(
        (const __attribute__((address_space(1))) unsigned int*)g,
        (__attribute__((address_space(3))) unsigned int*)l, 16, 0, 0);
}
__device__ __forceinline__ unsigned int cvt_pk_bf16(float a, float b) {
    unsigned int r;
    asm("v_cvt_pk_bf16_f32 %0, %1, %2" : "=v"(r) : "v"(a), "v"(b));
    return r;
}
__device__ __forceinline__ short8 pack8(float a0, float a1, float a2, float a3,
                                        float a4, float a5, float a6, float a7) {
    union { unsigned int u[4]; short8 s; } r;
    r.u[0] = cvt_pk_bf16(a0, a1); r.u[1] = cvt_pk_bf16(a2, a3);
    r.u[2] = cvt_pk_bf16(a4, a5); r.u[3] = cvt_pk_bf16(a6, a7);
    return r.s;
}

// bijective XCD swizzle (grid counts all divisible by 8 here; guarded anyway)
__device__ __forceinline__ int xcd_swizzle(int id, int nb) {
    if (nb & 7) return id;
    return (id & 7) * (nb >> 3) + (id >> 3);
}

// ---------------- fused weight conversion + rope table (one dispatch) -------------
__global__ void cvt_all(const float* __restrict__ wqkv, const float* __restrict__ wo,
                        const float* __restrict__ wi, const float* __restrict__ womlp,
                        u16* __restrict__ dqkv, u16* __restrict__ dwo,
                        u16* __restrict__ dinp, u16* __restrict__ dgate,
                        u16* __restrict__ dmlp, float2* __restrict__ tab) {
    int bid = blockIdx.x, tid = threadIdx.x;
    if (bid < 3072) {
        int i = (bid * 256 + tid) * 4;
        float4 v = *(const float4*)(wqkv + i);
        ushort4v o = {f2bf(v.x), f2bf(v.y), f2bf(v.z), f2bf(v.w)};
        *(ushort4v*)(dqkv + i) = o;
    } else if (bid < 4096) {
        int i = ((bid - 3072) * 256 + tid) * 4;
        float4 v = *(const float4*)(wo + i);
        ushort4v o = {f2bf(v.x), f2bf(v.y), f2bf(v.z), f2bf(v.w)};
        *(ushort4v*)(dwo + i) = o;
    } else if (bid < 4096 + 2 * FFP) {
        int seg = (bid - 4096) / FFP;          // 0: inp, 1: gate
        int row = (bid - 4096) % FFP;
        u16* dst = seg ? dgate : dinp;
        const float* src = wi + (size_t)(seg ? FF_ : 0) * DD;
        int c = tid * 4;
        ushort4v o = {0, 0, 0, 0};
        if (row < FF_) {
            float4 v = *(const float4*)(src + (size_t)row * DD + c);
            o.x = f2bf(v.x); o.y = f2bf(v.y); o.z = f2bf(v.z); o.w = f2bf(v.w);
        }
        *(ushort4v*)(dst + (size_t)row * DD + c) = o;
    } else if (bid < 4096 + 2 * FFP + 1024) {
        int row = bid - 4096 - 2 * FFP;        // 0..1023
        for (int c = tid * 4; c < FFP; c += 1024) {
            ushort4v o = {0, 0, 0, 0};
            if (c < FF_) {
                float4 v = *(const float4*)(womlp + (size_t)row * FF_ + c);
                o.x = f2bf(v.x); o.y = f2bf(v.y); o.z = f2bf(v.z); o.w = f2bf(v.w);
            }
            *(ushort4v*)(dmlp + (size_t)row * FFP + c) = o;
        }
    } else {
        // rope table: tab[mi*32 + i] = (cos, sin) of mi * 10000^(-i/32)
        int bq = bid - (4096 + 2 * FFP + 1024);   // 0..63
        int base = bq * 1024;
        for (int idx = tid; idx < 1024; idx += 256) {
            int e = base + idx;
            int mi = e >> 5, i = e & 31;
            float fr = (float)mi * powf(10000.0f, -(float)i / 32.0f);
            tab[e] = make_float2(cosf(fr), sinf(fr));
        }
    }
}

// ---------------- LayerNorm: fp32 in -> bf16 out ----------------------------------
__global__ void ln_kernel(const float* __restrict__ x, const float* __restrict__ w,
                          const float* __restrict__ b, u16* __restrict__ out) {
    int row = blockIdx.x;
    int tid = threadIdx.x;
    const float4 v = ((const float4*)(x + (size_t)row * DD))[tid];
    float s  = v.x + v.y + v.z + v.w;
    float ss = v.x*v.x + v.y*v.y + v.z*v.z + v.w*v.w;
    #pragma unroll
    for (int o = 32; o > 0; o >>= 1) { s += __shfl_down(s, o); ss += __shfl_down(ss, o); }
    __shared__ float sbuf[4], ssbuf[4];
    int wid = tid >> 6;
    if ((tid & 63) == 0) { sbuf[wid] = s; ssbuf[wid] = ss; }
    __syncthreads();
    float st  = sbuf[0] + sbuf[1] + sbuf[2] + sbuf[3];
    float sst = ssbuf[0] + ssbuf[1] + ssbuf[2] + ssbuf[3];
    float mean = st * (1.0f / DD);
    float var  = sst * (1.0f / DD) - mean * mean;
    float rstd = rsqrtf(var + 1e-5f);
    const float4 wv = ((const float4*)w)[tid];
    const float4 bv = ((const float4*)b)[tid];
    ushort4v o;
    o.x = f2bf((v.x - mean) * rstd * wv.x + bv.x);
    o.y = f2bf((v.y - mean) * rstd * wv.y + bv.y);
    o.z = f2bf((v.z - mean) * rstd * wv.z + bv.z);
    o.w = f2bf((v.w - mean) * rstd * wv.w + bv.w);
    ((ushort4v*)(out + (size_t)row * DD))[tid] = o;
}

// =============== depth-2 counted-vmcnt GEMM core (BK=32, 3 LDS buffers) ===========

// ---------------- std GEMM, BM=128 x BN=64: C = A[TxK] * W[NxK]^T -----------------
// MODE 0: +bias(optional fp32)   MODE 1: +add(fp32), fp32 out
template<int MODE, bool OUT_BF16>
__global__ __launch_bounds__(256, 4)
void mfma_gemm64(const u16* __restrict__ A, const u16* __restrict__ W,
                 const float* __restrict__ bias, const void* __restrict__ add,
                 void* __restrict__ Cout, int N, int K) {
    __shared__ u16 As[3][128 * 32];
    __shared__ u16 Bs[3][64 * 32];
    int tid = threadIdx.x;
    int w = tid >> 6, lane = tid & 63;
    int q = lane >> 4, m = lane & 15;

    int nbx = gridDim.x;
    int id = xcd_swizzle(blockIdx.y * nbx + blockIdx.x, nbx * gridDim.y);
    int bx = id % nbx, by = id / nbx;
    int row0 = by * 128, col0 = bx * 64;
    int wm = (w >> 1) * 64, wn = (w & 1) * 32;

    floatx4 acc[4][2];
    #pragma unroll
    for (int i = 0; i < 4; i++)
        #pragma unroll
        for (int j = 0; j < 2; j++)
            acc[i][j] = (floatx4){0.f, 0.f, 0.f, 0.f};

    int lrow = lane >> 2;
    int lcg  = (lane & 3) ^ ((lrow >> 1) & 3);
    const u16* Ag = A + (size_t)(row0 + w * 32 + lrow) * K + lcg * 8;
    const u16* Bg = W + (size_t)(col0 + w * 16 + lrow) * K + lcg * 8;
    int NT = K >> 5;
    int slot8 = (q ^ ((m >> 1) & 3)) * 8;

    auto stage = [&](int t, int buf) {
        const u16* Aq = Ag + (size_t)t * 32;
        const u16* Bq = Bg + (size_t)t * 32;
        gload_lds16(Aq,                  &As[buf][(w * 32) * 32]);
        gload_lds16(Aq + (size_t)16 * K, &As[buf][(w * 32 + 16) * 32]);
        gload_lds16(Bq,                  &Bs[buf][(w * 16) * 32]);
    };
    stage(0, 0); stage(1, 1);   // 6 loads/wave outstanding

    int cur = 0;
    for (int t = 0; t < NT; ++t) {
        if (t + 2 < NT) {
            int nxt = cur + 2; if (nxt >= 3) nxt -= 3;
            stage(t + 2, nxt);
            WAITVM(6);          // tile t landed; t+1,t+2 in flight
        } else if (t + 2 == NT) {
            WAITVM(3);
        } else {
            WAITVM(0);
        }
        __builtin_amdgcn_s_barrier();
        CFENCE();
        short8 af[4], bf[2];
        #pragma unroll
        for (int f = 0; f < 4; f++)
            af[f] = *(const short8*)&As[cur][(wm + f * 16 + m) * 32 + slot8];
        #pragma unroll
        for (int f = 0; f < 2; f++)
            bf[f] = *(const short8*)&Bs[cur][(wn + f * 16 + m) * 32 + slot8];
        __builtin_amdgcn_s_setprio(1);
        #pragma unroll
        for (int mf = 0; mf < 4; mf++)
            #pragma unroll
            for (int nf = 0; nf < 2; nf++)
                acc[mf][nf] = __builtin_amdgcn_mfma_f32_16x16x32_bf16(
                    af[mf], bf[nf], acc[mf][nf], 0, 0, 0);
        __builtin_amdgcn_s_setprio(0);
        if (t + 1 < NT) {
            __builtin_amdgcn_s_barrier();   // reads of buf[cur] done before restage
            CFENCE();
        }
        cur = (cur + 1 == 3) ? 0 : cur + 1;
    }

    #pragma unroll
    for (int nf = 0; nf < 2; nf++) {
        int col = col0 + wn + nf * 16 + m;
        float bv = 0.f;
        if (MODE == 0 && bias) bv = bias[col];
        #pragma unroll
        for (int mf = 0; mf < 4; mf++) {
            #pragma unroll
            for (int r = 0; r < 4; r++) {
                int row = row0 + wm + mf * 16 + q * 4 + r;
                size_t idx = (size_t)row * N + col;
                float vacc = acc[mf][nf][r] + bv;
                if (MODE == 1) vacc += ((const float*)add)[idx];
                if (OUT_BF16) ((u16*)Cout)[idx] = f2bf(vacc);
                else          ((float*)Cout)[idx] = vacc;
            }
        }
    }
}

// ---------------- fused QKV GEMM (BM=128 x BN=64) + bias + RoPE + scatter ---------
__global__ __launch_bounds__(256, 4)
void mfma_gemm_qkv(const u16* __restrict__ A, const u16* __restrict__ W,
                   const float* __restrict__ bias, const float2* __restrict__ tab,
                   u16* __restrict__ qb, u16* __restrict__ kb, u16* __restrict__ vtb) {
    __shared__ u16 As[3][128 * 32];
    __shared__ u16 Bs[3][64 * 32];
    int tid = threadIdx.x;
    int w = tid >> 6, lane = tid & 63;
    int q = lane >> 4, m = lane & 15;

    int nbx = gridDim.x;
    int id = xcd_swizzle(blockIdx.y * nbx + blockIdx.x, nbx * gridDim.y);
    int bx = id % nbx, by = id / nbx;
    int row0 = by * 128, col0 = bx * 64;
    int wm = w * 32;

    floatx4 acc[2][4];
    #pragma unroll
    for (int i = 0; i < 2; i++)
        #pragma unroll
        for (int j = 0; j < 4; j++)
            acc[i][j] = (floatx4){0.f, 0.f, 0.f, 0.f};

    int lrow = lane >> 2;
    int lcg  = (lane & 3) ^ ((lrow >> 1) & 3);
    const u16* Ag = A + (size_t)(row0 + w * 32 + lrow) * DD + lcg * 8;
    const u16* Bg = W + (size_t)(col0 + w * 16 + lrow) * DD + lcg * 8;
    const int NT = DD >> 5;   // 32
    int slot8 = (q ^ ((m >> 1) & 3)) * 8;

    auto stage = [&](int t, int buf) {
        const u16* Aq = Ag + (size_t)t * 32;
        const u16* Bq = Bg + (size_t)t * 32;
        gload_lds16(Aq,                   &As[buf][(w * 32) * 32]);
        gload_lds16(Aq + (size_t)16 * DD, &As[buf][(w * 32 + 16) * 32]);
        gload_lds16(Bq,                   &Bs[buf][(w * 16) * 32]);
    };
    stage(0, 0); stage(1, 1);

    int cur = 0;
    for (int t = 0; t < NT; ++t) {
        if (t + 2 < NT) {
            int nxt = cur + 2; if (nxt >= 3) nxt -= 3;
            stage(t + 2, nxt);
            WAITVM(6);
        } else if (t + 2 == NT) {
            WAITVM(3);
        } else {
            WAITVM(0);
        }
        __builtin_amdgcn_s_barrier();
        CFENCE();
        short8 af[2], bf[4];
        #pragma unroll
        for (int f = 0; f < 2; f++)
            af[f] = *(const short8*)&As[cur][(wm + f * 16 + m) * 32 + slot8];
        #pragma unroll
        for (int f = 0; f < 4; f++)
            bf[f] = *(const short8*)&Bs[cur][(f * 16 + m) * 32 + slot8];
        __builtin_amdgcn_s_setprio(1);
        #pragma unroll
        for (int mf = 0; mf < 2; mf++)
            #pragma unroll
            for (int nf = 0; nf < 4; nf++)
                acc[mf][nf] = __builtin_amdgcn_mfma_f32_16x16x32_bf16(
                    af[mf], bf[nf], acc[mf][nf], 0, 0, 0);
        __builtin_amdgcn_s_setprio(0);
        if (t + 1 < NT) {
            __builtin_amdgcn_s_barrier();
            CFENCE();
        }
        cur = (cur + 1 == 3) ? 0 : cur + 1;
    }

    // ---- fused epilogue ----
    int seg = col0 >> 6;             // 0..15 q, 16..31 k, 32..47 v
    int b   = row0 >> 11;            // batch (uniform per block)
    int mi0 = (row0 & 2047) + wm;

    float b0[4];
    #pragma unroll
    for (int nf = 0; nf < 4; nf++) b0[nf] = bias[col0 + nf * 16 + m];

    if (seg < 32) {
        int hq = seg & 15;
        u16* dst = (seg < 16 ? qb : kb) + (size_t)(b * HH + hq) * MM * DHH;
        #pragma unroll
        for (int mf = 0; mf < 2; mf++) {
            #pragma unroll
            for (int r = 0; r < 4; r++) {
                int mi = mi0 + mf * 16 + q * 4 + r;
                float2 cs0 = tab[mi * 32 + m];        // pair (m, m+32)
                float2 cs1 = tab[mi * 32 + 16 + m];   // pair (16+m, 48+m)
                float a0 = acc[mf][0][r] + b0[0];
                float a1 = acc[mf][1][r] + b0[1];
                float a2 = acc[mf][2][r] + b0[2];
                float a3 = acc[mf][3][r] + b0[3];
                size_t base = (size_t)mi * DHH;
                dst[base + m]      = f2bf(a0 * cs0.x - a2 * cs0.y);
                dst[base + 32 + m] = f2bf(a0 * cs0.y + a2 * cs0.x);
                dst[base + 16 + m] = f2bf(a1 * cs1.x - a3 * cs1.y);
                dst[base + 48 + m] = f2bf(a1 * cs1.y + a3 * cs1.x);
            }
        }
    } else {
        int hv = seg & 15;
        u16* dst = vtb + (size_t)(b * HH + hv) * DHH * MM;
        #pragma unroll
        for (int nf = 0; nf < 4; nf++) {
            int d = nf * 16 + m;
            #pragma unroll
            for (int mf = 0; mf < 2; mf++) {
                int mi = mi0 + mf * 16 + q * 4;
                ushort4v o;
                o.x = f2bf(acc[mf][nf][0] + b0[nf]);
                o.y = f2bf(acc[mf][nf][1] + b0[nf]);
                o.z = f2bf(acc[mf][nf][2] + b0[nf]);
                o.w = f2bf(acc[mf][nf][3] + b0[nf]);
                *(ushort4v*)(dst + (size_t)d * MM + mi) = o;
            }
        }
    }
}

// ---------------- dual-B MLP GEMM (BM=128 x BN=64): gelu(A Wi^T) * (A Wg^T) -------
__global__ __launch_bounds__(256, 3)
void mfma_gemm_glu(const u16* __restrict__ A, const u16* __restrict__ W1,
                   const u16* __restrict__ W2, u16* __restrict__ Cout) {
    __shared__ u16 As [3][128 * 32];
    __shared__ u16 B1s[3][64 * 32];
    __shared__ u16 B2s[3][64 * 32];
    int tid = threadIdx.x;
    int w = tid >> 6, lane = tid & 63;
    int q = lane >> 4, m = lane & 15;

    int nbx = gridDim.x;
    int id = xcd_swizzle(blockIdx.y * nbx + blockIdx.x, nbx * gridDim.y);
    int bx = id % nbx, by = id / nbx;
    int row0 = by * 128, col0 = bx * 64;
    int wm = (w >> 1) * 64, wn = (w & 1) * 32;

    floatx4 acc1[4][2], acc2[4][2];
    #pragma unroll
    for (int i = 0; i < 4; i++)
        #pragma unroll
        for (int j = 0; j < 2; j++) {
            acc1[i][j] = (floatx4){0.f, 0.f, 0.f, 0.f};
            acc2[i][j] = (floatx4){0.f, 0.f, 0.f, 0.f};
        }

    int lrow = lane >> 2;
    int lcg  = (lane & 3) ^ ((lrow >> 1) & 3);
    const u16* Ag  = A  + (size_t)(row0 + w * 32 + lrow) * DD + lcg * 8;
    const u16* B1g = W1 + (size_t)(col0 + w * 16 + lrow) * DD + lcg * 8;
    const u16* B2g = W2 + (size_t)(col0 + w * 16 + lrow) * DD + lcg * 8;
    const int NT = DD >> 5;   // 32
    int slot8 = (q ^ ((m >> 1) & 3)) * 8;

    auto stage = [&](int t, int buf) {
        const u16* Aq  = Ag  + (size_t)t * 32;
        const u16* B1q = B1g + (size_t)t * 32;
        const u16* B2q = B2g + (size_t)t * 32;
        gload_lds16(Aq,                   &As [buf][(w * 32) * 32]);
        gload_lds16(Aq + (size_t)16 * DD, &As [buf][(w * 32 + 16) * 32]);
        gload_lds16(B1q,                  &B1s[buf][(w * 16) * 32]);
        gload_lds16(B2q,                  &B2s[buf][(w * 16) * 32]);
    };
    stage(0, 0); stage(1, 1);   // 8 loads/wave outstanding

    int cur = 0;
    for (int t = 0; t < NT; ++t) {
        if (t + 2 < NT) {
            int nxt = cur + 2; if (nxt >= 3) nxt -= 3;
            stage(t + 2, nxt);
            WAITVM(8);          // tile t landed; t+1,t+2 (8 loads) in flight
        } else if (t + 2 == NT) {
            WAITVM(4);
        } else {
            WAITVM(0);
        }
        __builtin_amdgcn_s_barrier();
        CFENCE();
        short8 af[4], b1f[2], b2f[2];
        #pragma unroll
        for (int f = 0; f < 4; f++)
            af[f] = *(const short8*)&As[cur][(wm + f * 16 + m) * 32 + slot8];
        #pragma unroll
        for (int f = 0; f < 2; f++) {
            b1f[f] = *(const short8*)&B1s[cur][(wn + f * 16 + m) * 32 + slot8];
            b2f[f] = *(const short8*)&B2s[cur][(wn + f * 16 + m) * 32 + slot8];
        }
        __builtin_amdgcn_s_setprio(1);
        #pragma unroll
        for (int mf = 0; mf < 4; mf++)
            #pragma unroll
            for (int nf = 0; nf < 2; nf++) {
                acc1[mf][nf] = __builtin_amdgcn_mfma_f32_16x16x32_bf16(
                    af[mf], b1f[nf], acc1[mf][nf], 0, 0, 0);
                acc2[mf][nf] = __builtin_amdgcn_mfma_f32_16x16x32_bf16(
                    af[mf], b2f[nf], acc2[mf][nf], 0, 0, 0);
            }
        __builtin_amdgcn_s_setprio(0);
        if (t + 1 < NT) {
            __builtin_amdgcn_s_barrier();
            CFENCE();
        }
        cur = (cur + 1 == 3) ? 0 : cur + 1;
    }

    #pragma unroll
    for (int nf = 0; nf < 2; nf++) {
        int col = col0 + wn + nf * 16 + m;
        #pragma unroll
        for (int mf = 0; mf < 4; mf++) {
            #pragma unroll
            for (int r = 0; r < 4; r++) {
                int row = row0 + wm + mf * 16 + q * 4 + r;
                Cout[(size_t)row * FFP + col] =
                    f2bf(gelu_exact(acc1[mf][nf][r]) * acc2[mf][nf][r]);
            }
        }
    }
}

// ---------------- MFMA flash attention, 32x32 swapped-QK^T, 1-barrier/tile --------
// 4 waves x 32 Q-rows (128/block, grid 512). Swapped QK^T + in-register softmax,
// sigma-staged K (verified R5). NEW: 3 LDS buffers (48 KB -> 3 blocks/CU) with
// ONE barrier per tile. Race-free by skew analysis: body = {vmcnt; barrier(t);
// compute buf[t%3]; stage t+2 -> buf[(t+2)%3]}. Max skew under 1 barrier = 1 iter;
// writer of (t+2)%3 = (t-1)%3 is ordered after barrier(t), which guarantees all
// compute(t-1) reads done. Readers hold t%3 and (t+1)%3 -- disjoint.
__global__ __launch_bounds__(256, 3)
void flash_attn_mfma32(const u16* __restrict__ qp, const u16* __restrict__ kp,
                       const u16* __restrict__ vt, const int* __restrict__ mask,
                       u16* __restrict__ out) {
    __shared__ __align__(16) u16 Ks[3 * 64 * 64];   // [buf][kv(sigma)][chunk swz row&7]
    __shared__ __align__(16) u16 Vs[3 * 64 * 64];   // [buf][d][kv chunk swz row&7]

    int tid = threadIdx.x;
    int w = tid >> 6, lane = tid & 63;
    int col = lane & 31, hi = lane >> 5;
    int mt = blockIdx.x, h = blockIdx.y, b = blockIdx.z;
    int m0 = mt * 128;
    size_t bh = (size_t)(b * HH + h);
    const u16* qg  = qp + (bh * MM + m0 + w * 32) * DHH;
    const u16* kg  = kp + bh * MM * DHH;
    const u16* vtg = vt + bh * DHH * MM;

    // number of valid 64-aligned KV tiles (monotone mask; uniform scalar loads)
    int ntv = 0;
    for (int n = 0; n < MM; n += 64) ntv += (mask[b * MM + n] != 0);

    // Q fragments straight to registers: B-operand Q[qrow=col][k=(2t+hi)*8..+7]
    short8 qf[4];
    #pragma unroll
    for (int t = 0; t < 4; t++)
        qf[t] = *(const short8*)(qg + (size_t)col * DHH + (2 * t + hi) * 8);

    // staging geometry: each gload = 8 LDS rows x 8 chunks; chunk pre-swizzle c^(row&7)
    int lr = lane >> 3, lc = lane & 7;
    int lcg = lc ^ lr;
    int i0 = w * 16 + lr, i1 = i0 + 8;          // this wave's LDS rows
    int sg0 = (i0 & ~12) | ((i0 & 4) << 1) | ((i0 & 8) >> 1);   // sigma(i0)
    int sg1 = (i1 & ~12) | ((i1 & 4) << 1) | ((i1 & 8) >> 1);   // sigma(i1)
    const u16* Kg0 = kg + (size_t)sg0 * DHH + lcg * 8;
    const u16* Kg1 = kg + (size_t)sg1 * DHH + lcg * 8;
    const u16* Vg0 = vtg + (size_t)i0 * MM + lcg * 8;
    const u16* Vg1 = vtg + (size_t)i1 * MM + lcg * 8;
    u16* KL0 = Ks + (w * 16) * 64;
    u16* KL1 = KL0 + 8 * 64;
    u16* VL0 = Vs + (w * 16) * 64;
    u16* VL1 = VL0 + 8 * 64;
    const int BUFO = 64 * 64;   // u16 elements per buffer

    auto stage_tile = [&](int t, int buf) {   // 4 gloads/wave
        size_t nk = (size_t)t * 64;
        int o = buf * BUFO;
        gload_lds16(Kg0 + nk * DHH, KL0 + o);
        gload_lds16(Kg1 + nk * DHH, KL1 + o);
        gload_lds16(Vg0 + nk,       VL0 + o);
        gload_lds16(Vg1 + nk,       VL1 + o);
    };

    floatx16 O0, O1;
    #pragma unroll
    for (int r = 0; r < 16; r++) { O0[r] = 0.f; O1[r] = 0.f; }
    float ls = 0.f;

    int swz = (col & 7) * 8;    // chunk-swizzle term for frag reads

    auto compute_tile = [&](int co) {
        // ---- St = K(sigma) . Q^T : lane owns Q-row `col`, 16 kv per lane ----
        floatx16 P0, P1;
        #pragma unroll
        for (int r = 0; r < 16; r++) { P0[r] = 0.f; P1[r] = 0.f; }
        #pragma unroll
        for (int t = 0; t < 4; t++) {
            int ck = (((2 * t + hi) * 8) ^ swz);
            short8 kf0 = *(const short8*)&Ks[co + col * 64 + ck];
            short8 kf1 = *(const short8*)&Ks[co + (32 + col) * 64 + ck];
            __builtin_amdgcn_s_setprio(1);
            P0 = __builtin_amdgcn_mfma_f32_32x32x16_bf16(kf0, qf[t], P0, 0, 0, 0);
            P1 = __builtin_amdgcn_mfma_f32_32x32x16_bf16(kf1, qf[t], P1, 0, 0, 0);
            __builtin_amdgcn_s_setprio(0);
        }
        // ---- max-free softmax, in-register; per-lane scalar denominator ----
        #pragma unroll
        for (int r = 0; r < 16; r++) {
            float e0 = exp2f(P0[r] * SCALE2);
            float e1 = exp2f(P1[r] * SCALE2);
            P0[r] = e0; P1[r] = e1;
            ls += e0 + e1;
        }
        // ---- pack P to bf16 A-fragments (sigma makes reg order = frag order) ----
        short8 pa0 = pack8(P0[0], P0[1], P0[2],  P0[3],  P0[4],  P0[5],  P0[6],  P0[7]);
        short8 pa1 = pack8(P0[8], P0[9], P0[10], P0[11], P0[12], P0[13], P0[14], P0[15]);
        short8 pa2 = pack8(P1[0], P1[1], P1[2],  P1[3],  P1[4],  P1[5],  P1[6],  P1[7]);
        short8 pa3 = pack8(P1[8], P1[9], P1[10], P1[11], P1[12], P1[13], P1[14], P1[15]);
        // ---- O += P V  (B-operand Vt[d][kv]) ----
        #pragma unroll
        for (int s = 0; s < 4; s++) {
            int ck = (((2 * s + hi) * 8) ^ swz);
            short8 vf0 = *(const short8*)&Vs[co + col * 64 + ck];
            short8 vf1 = *(const short8*)&Vs[co + (32 + col) * 64 + ck];
            short8 pas = (s == 0) ? pa0 : (s == 1) ? pa1 : (s == 2) ? pa2 : pa3;
            __builtin_amdgcn_s_setprio(1);
            O0 = __builtin_amdgcn_mfma_f32_32x32x16_bf16(pas, vf0, O0, 0, 0, 0);
            O1 = __builtin_amdgcn_mfma_f32_32x32x16_bf16(pas, vf1, O1, 0, 0, 0);
            __builtin_amdgcn_s_setprio(0);
        }
    };

    // prologue: stage tiles 0,1 into bufs 0,1 (8 gloads/wave; rows 64..127 of
    // kb/vtb always exist even when ntv<2, values simply unused)
    stage_tile(0, 0);
    stage_tile(1, 1);

    int cur = 0;
    for (int t = 0; t < ntv; ++t) {
        if (t + 1 < ntv) WAITVM(4);   // own tile-t loads landed; t+1 in flight
        else             WAITVM(0);
        __builtin_amdgcn_s_barrier();  // all waves' tile-t rows landed
        CFENCE();
        compute_tile(cur * BUFO);
        if (t + 2 < ntv) {             // stage AFTER compute: writer = (t+2)%3,
            int nxt = cur + 2;         // concurrent readers hold t%3,(t+1)%3
            if (nxt >= 3) nxt -= 3;
            stage_tile(t + 2, nxt);
        }
        CFENCE();
        cur = (cur + 1 == 3) ? 0 : cur + 1;
    }
    WAITVM(0);      // drain stray prefetch before LDS goes out of scope
    CFENCE();

    // ---- epilogue: denominator = sum over both hi-halves of the Q-row ----
    ls += __shfl_xor(ls, 32);
    float inv = 1.0f / ls;              // valid for qrow = col (both hi lanes)
    float invr[16];
    #pragma unroll
    for (int r = 0; r < 16; r++) {
        int crow = (r & 3) + 8 * (r >> 2) + 4 * hi;   // O-row for this reg
        invr[r] = __shfl(inv, crow, 64);
    }
    u16* ob = out + ((size_t)(b * MM) + m0 + w * 32) * DD + h * DHH;
    #pragma unroll
    for (int r = 0; r < 16; r++) {
        int crow = (r & 3) + 8 * (r >> 2) + 4 * hi;
        ob[(size_t)crow * DD + col]      = f2bf(O0[r] * invr[r]);
        ob[(size_t)crow * DD + 32 + col] = f2bf(O1[r] * invr[r]);
    }
}

extern "C" void kernel_launch(void* const* d_in, const int* in_sizes, int n_in,
                              void* d_out, int out_size, void* d_ws, size_t ws_size,
                              hipStream_t stream) {
    const float* hidden   = (const float*)d_in[0];
    const int*   mask     = (const int*)d_in[1];
    const float* ln1_w    = (const float*)d_in[2];
    const float* ln1_b    = (const float*)d_in[3];
    const float* wqkv_w   = (const float*)d_in[4];
    const float* wqkv_b   = (const float*)d_in[5];
    const float* wo_w     = (const float*)d_in[6];
    const float* ln2_w    = (const float*)d_in[7];
    const float* ln2_b    = (const float*)d_in[8];
    const float* wi_w     = (const float*)d_in[9];
    const float* wo_mlp_w = (const float*)d_in[10];
    float* out = (float*)d_out;

    char* ws = (char*)d_ws;
    u16* wqkv_bf  = (u16*)(ws);                         //  6.00 MB
    u16* wo_bf    = (u16*)(ws + 6291456);               //  2.00 MB
    u16* wi_inp   = (u16*)(ws + 8388608);               //  5.25 MB
    u16* wi_gate  = (u16*)(ws + 13893632);              //  5.25 MB
    u16* womlp_bf = (u16*)(ws + 19398656);              //  5.25 MB
    u16* xn       = (u16*)(ws + 24903680);              //  8 MB [4096][1024]
    float2* rtab  = (float2*)(ws + 33292288);           //  512 KB rope table
    u16* qb       = (u16*)(ws + 58458112);              //  8 MB (B,H,M,DH)
    u16* kb       = (u16*)(ws + 66846720);              //  8 MB
    u16* vtb      = (u16*)(ws + 75235328);              //  8 MB (B,H,DH,M)
    u16* attn_out = (u16*)(ws + 83623936);              //  8 MB
    u16* hb       = (u16*)(ws + 92012544);              //  8 MB
    u16* act      = (u16*)(ws + 58458112);              // 22 MB, reuses qb/kb/vt

    // 0. all weight conversions + rope table (one dispatch)
    cvt_all<<<4096 + 2 * FFP + 1024 + 64, 256, 0, stream>>>(
        wqkv_w, wo_w, wi_w, wo_mlp_w, wqkv_bf, wo_bf, wi_inp, wi_gate, womlp_bf, rtab);
    // 1. LN1
    ln_kernel<<<TT, 256, 0, stream>>>(hidden, ln1_w, ln1_b, xn);
    // 2. fused QKV GEMM + bias + RoPE + V-transpose scatter  (1536 blocks)
    mfma_gemm_qkv<<<dim3(3 * DD / 64, TT / 128), 256, 0, stream>>>(
        xn, wqkv_bf, wqkv_b, rtab, qb, kb, vtb);
    // 3. MFMA flash attention, 32x32 swapped, 3-buf 1-barrier (512 blocks)
    flash_attn_mfma32<<<dim3(MM / 128, HH, BB), 256, 0, stream>>>(
        qb, kb, vtb, mask, attn_out);
    // 4. x1 = hidden + attn_out @ Wo^T -> d_out (fp32)   (512 blocks)
    mfma_gemm64<1, false><<<dim3(DD / 64, TT / 128), 256, 0, stream>>>(
        attn_out, wo_bf, nullptr, hidden, out, DD, DD);
    // 5. LN2
    ln_kernel<<<TT, 256, 0, stream>>>(out, ln2_w, ln2_b, hb);
    // 6. act = gelu(h@Wi^T) * (h@Wg^T)  BN=64 LDS GEMM (1344 blocks) -- R5 optimum
    mfma_gemm_glu<<<dim3(FFP / 64, TT / 128), 256, 0, stream>>>(
        hb, wi_inp, wi_gate, act);
    // 7. out = out + act @ Wo_mlp^T   (512 blocks)
    mfma_gemm64<1, false><<<dim3(DD / 64, TT / 128), 256, 0, stream>>>(
        act, womlp_bf, nullptr, out, out, DD, FFP);
}